// Round 8
// baseline (1322.856 us; speedup 1.0000x reference)
//
#include <hip/hip_runtime.h>
#include <hip/hip_cooperative_groups.h>
#include <hip/hip_bf16.h>
#include <stdint.h>
#include <stddef.h>

namespace cg = cooperative_groups;

static constexpr int BB = 16, NN = 256, TT = 4, HH = 128;
static constexpr int MM = BB * NN;     // 4096 rows
static constexpr int CC = 512;         // 4*H gate width
static constexpr int OUTV = 1000;
static constexpr int MAXS = 15;
static constexpr int SP = 132;         // f32 state row pitch in LDS
static constexpr int SSZ = MM * HH;    // one state buffer (f32 elems)

typedef float f32x4 __attribute__((ext_vector_type(4)));
typedef short s16x8 __attribute__((ext_vector_type(8)));

__device__ __forceinline__ float sigf(float x) { return 1.0f / (1.0f + __expf(-x)); }
__device__ __forceinline__ float tanhr(float x) { return 2.0f / (1.0f + __expf(-2.0f * x)) - 1.0f; }
__device__ __forceinline__ unsigned short f2bu(float a) {
  return __builtin_bit_cast(unsigned short, __float2bfloat16(a));
}

// One persistent cooperative kernel: setup -> 16 step iterations -> final logits.
// 256 blocks x 512 threads (8 waves) = 1 block/CU. Block owns 16 rows (nodes).
// Wave w owns gate-columns kcol = w*16+n16 of ALL four gates (tiles ci = w+8g),
// so LSTM gate math stays in MFMA D registers; c-state in regs; h via LDS bf16 frags.
__global__ __launch_bounds__(512, 2) void mega_kernel(
    const int* __restrict__ data, const int* __restrict__ tb, const int* __restrict__ fb,
    const int* __restrict__ exi, const int* __restrict__ steps,
    const float* __restrict__ embed, const float* __restrict__ Wi, const float* __restrict__ Wh,
    const float* __restrict__ bl, const float* __restrict__ Wb, const float* __restrict__ bbp,
    const float* __restrict__ Wo, const float* __restrict__ bo,
    float* __restrict__ out, float* __restrict__ ws) {
  cg::grid_group grid = cg::this_grid();
  const int blk = blockIdx.x;   // 0..255
  const int tid = threadIdx.x;  // 0..511

  // ---- workspace carve (all written before read each launch) ----
  float* tab = ws;                                   // 1024*CC f32 (x@Wi0+b0 per vocab row)
  float* WAb = ws + (size_t)1024 * CC;               // 4*SSZ (parity A state bufs)
  float* WBb = WAb + 4 * (size_t)SSZ;                // 4*SSZ (parity B)
  unsigned short* swz = (unsigned short*)(WBb + 4 * (size_t)SSZ);  // 3*65536 bf16
  float* wtwf = (float*)(swz + 3 * 65536);           // wtA,wfA,wtB,wfB (MM each)
  int* offs = (int*)(wtwf + 4 * MM);                 // MM+16
  int* edges = offs + MM + 16;                       // 2*MM
  float* fin = (float*)(edges + 2 * MM);             // 16*512 final exit feats

  const float* Wi0 = Wi;
  const float* Wi1 = Wi + HH * CC;
  const float* Wh0 = Wh;
  const float* Wh1 = Wh + HH * CC;
  const float* b0 = bl;
  const float* b1 = bl + CC;
  unsigned short* swzWh0 = swz;
  unsigned short* swzWi1 = swz + 65536;
  unsigned short* swzWh1 = swz + 2 * 65536;
  float* wtA = wtwf;          float* wfA = wtwf + MM;
  float* wtB = wtwf + 2 * MM; float* wfB = wtwf + 3 * MM;

  __shared__ float c0L[16 * SP], h0L[16 * SP], c1L[16 * SP], h1L[16 * SP];
  __shared__ __align__(16) unsigned short hA0[2048], hA1[2048];  // 16 rows x 128 k, frag order
  __shared__ float exitP[512];
  __shared__ float ipL[16];
  __shared__ int toks[64];

  // ================= setup phase =================
  // weight swizzle into bf16 B-fragment order (all blocks)
  for (int i = blk * 512 + tid; i < 3 * 65536; i += 256 * 512) {
    int mtx = i >> 16, ii = i & 65535;
    const float* W = (mtx == 0) ? Wh0 : (mtx == 1) ? Wi1 : Wh1;
    int j = ii & 7, ln = (ii >> 3) & 63, kb = (ii >> 9) & 3, ct = ii >> 11;
    int n = ln & 15, q = ln >> 4;
    swz[i] = f2bu(W[(kb * 32 + q * 8 + j) * CC + ct * 16 + n]);
  }
  // per-batch CSR build, entirely block-local in LDS (blocks 0..15)
  if (blk < 16) {
    int* cnt = (int*)h0L;
    int* sc = cnt + 256;
    int* cur = cnt + 512;
    if (tid < 256) cnt[tid] = 0;
    __syncthreads();
    const int n = tid >> 1, bit = tid & 1;
    const int tgt = bit ? fb[blk * NN + n] : tb[blk * NN + n];
    atomicAdd(&cnt[tgt], 1);
    __syncthreads();
    if (tid < 256) sc[tid] = cnt[tid];
    __syncthreads();
    for (int ofs = 1; ofs < 256; ofs <<= 1) {
      int t2 = (tid < 256 && tid >= ofs) ? sc[tid - ofs] : 0;
      __syncthreads();
      if (tid < 256) sc[tid] += t2;
      __syncthreads();
    }
    if (tid < 256) { offs[blk * NN + tid] = blk * 2 * NN + sc[tid] - cnt[tid]; cur[tid] = 0; }
    if (blk == 0 && tid == 0) offs[MM] = 2 * MM;
    __syncthreads();
    int lpos = sc[tgt] - cnt[tgt] + atomicAdd(&cur[tgt], 1);
    edges[blk * 2 * NN + lpos] = (n << 1) | bit;
  }
  // XW0 vocab table: tab[v] = embed[v]@Wi0 + b0 (blocks 0..249, 4 rows each)
  if (blk < 250) {
    float* A = c0L;  // 512 staged embed values (4 rows x 128)
    const int v0 = blk * 4;
    A[tid] = embed[(size_t)(v0 + (tid >> 7)) * HH + (tid & 127)];
    __syncthreads();
    const int j = tid;
    float a0 = b0[j], a1 = a0, a2 = a0, a3 = a0;
#pragma unroll 4
    for (int k = 0; k < HH; ++k) {
      float wv = Wi0[k * CC + j];
      a0 += A[k] * wv; a1 += A[128 + k] * wv; a2 += A[256 + k] * wv; a3 += A[384 + k] * wv;
    }
    tab[(size_t)v0 * CC + j] = a0;
    tab[(size_t)(v0 + 1) * CC + j] = a1;
    tab[(size_t)(v0 + 2) * CC + j] = a2;
    tab[(size_t)(v0 + 3) * CC + j] = a3;
  }
  if (tid < 64) toks[tid] = data[(blk * 16 + (tid >> 2)) * TT + (tid & 3)];

  grid.sync();

  // ================= per-block constants (persist across all steps) =================
  const int row0 = blk * 16;
  const int b = row0 >> 8;
  const int sb = steps[b];
  const int exnode = exi[b];
  const int exm = exnode - (row0 & (NN - 1));
  const int w = tid >> 6, lane = tid & 63;
  const int n16 = lane & 15, qq = lane >> 4;
  const int kcol = w * 16 + n16;
  const int basePos = ((kcol >> 5) * 64 + ((kcol >> 3) & 3) * 16) * 8 + (kcol & 7);

  const s16x8* pWh0 = (const s16x8*)swzWh0;
  const s16x8* pWh1 = (const s16x8*)swzWh1;
  const s16x8* pWi1 = (const s16x8*)swzWi1;
  s16x8 B0f[4][4], B1f[4][4];
  float b1v[4];
#pragma unroll
  for (int g = 0; g < 4; ++g) {
    int ci = w + 8 * g;
#pragma unroll
    for (int kb = 0; kb < 4; ++kb) {
      B0f[g][kb] = pWh0[(ci * 4 + kb) * 64 + lane];
      B1f[g][kb] = pWh1[(ci * 4 + kb) * 64 + lane];
    }
    b1v[g] = b1[ci * 16 + n16];
  }
  const s16x8* hA0v = (const s16x8*)hA0;
  const s16x8* hA1v = (const s16x8*)hA1;

  // ================= step loop =================
  for (int s = 0; s <= MAXS; ++s) {
    if (s) grid.sync();
    const bool aggLive = (s >= 1) && ((s - 1) < sb);
    const bool lstmLive = s < sb;
    if (!aggLive && !lstmLive) continue;

    float* Ww0 = ((s & 1) ? WBb : WAb);             float* Ww1 = Ww0 + SSZ;
    float* Ww2 = Ww0 + 2 * SSZ;                     float* Ww3 = Ww0 + 3 * SSZ;
    const float* Wr0 = ((s & 1) ? WAb : WBb);       const float* Wr1 = Wr0 + SSZ;
    const float* Wr2 = Wr0 + 2 * SSZ;               const float* Wr3 = Wr0 + 3 * SSZ;
    float* wtWp = (s & 1) ? wtB : wtA;              float* wfWp = (s & 1) ? wfB : wfA;
    const float* wtRp = (s & 1) ? wtA : wtB;        const float* wfRp = (s & 1) ? wfA : wfB;

    // ----- prologue: aggregate previous step (16 nodes, 32 lanes each)
    if (aggLive) {
      const int l = tid & 31;
      const int m = tid >> 5;
      const int node = row0 + m;
      int beg = offs[node], end = offs[node + 1];
      float a0x = 0.f, a0y = 0.f, a0z = 0.f, a0w = 0.f;
      float a1x = 0.f, a1y = 0.f, a1z = 0.f, a1w = 0.f;
      float a2x = 0.f, a2y = 0.f, a2z = 0.f, a2w = 0.f;
      float a3x = 0.f, a3y = 0.f, a3z = 0.f, a3w = 0.f;
      float wsum = 0.f;
      for (int e = beg; e < end; ++e) {
        int rec = edges[e];
        int src = (b << 8) + (rec >> 1);
        float wv = (rec & 1) ? wfRp[src] : wtRp[src];
        wsum += wv;
        float4 x0 = ((const float4*)Wr0)[src * 32 + l];
        float4 x1 = ((const float4*)Wr1)[src * 32 + l];
        float4 x2 = ((const float4*)Wr2)[src * 32 + l];
        float4 x3 = ((const float4*)Wr3)[src * 32 + l];
        a0x += wv * x0.x; a0y += wv * x0.y; a0z += wv * x0.z; a0w += wv * x0.w;
        a1x += wv * x1.x; a1y += wv * x1.y; a1z += wv * x1.z; a1w += wv * x1.w;
        a2x += wv * x2.x; a2y += wv * x2.y; a2z += wv * x2.z; a2w += wv * x2.w;
        a3x += wv * x3.x; a3y += wv * x3.y; a3z += wv * x3.z; a3w += wv * x3.w;
      }
      float inv = 1.0f / (wsum + 1e-7f);
      float4 o0 = { a0x * inv, a0y * inv, a0z * inv, a0w * inv };
      float4 o1 = { a1x * inv, a1y * inv, a1z * inv, a1w * inv };
      float4 o2 = { a2x * inv, a2y * inv, a2z * inv, a2w * inv };
      float4 o3 = { a3x * inv, a3y * inv, a3z * inv, a3w * inv };
      ((float4*)c0L)[m * (SP / 4) + l] = o0;
      ((float4*)h0L)[m * (SP / 4) + l] = o1;
      ((float4*)c1L)[m * (SP / 4) + l] = o2;
      ((float4*)h1L)[m * (SP / 4) + l] = o3;
      if (l == 0) ipL[m] = wsum;
      // batch death: persist exit-node feats for the final logits.
      // NOTE: node is a GLOBAL row index; exnode is LOCAL (0..255) -> compare in local space.
      if (!lstmLive && ((node & (NN - 1)) == exnode)) {
        ((float4*)(fin + b * 512))[l] = o0;
        ((float4*)(fin + b * 512 + 128))[l] = o1;
        ((float4*)(fin + b * 512 + 256))[l] = o2;
        ((float4*)(fin + b * 512 + 384))[l] = o3;
      }
    } else {
      // s == 0: zero states, initial ip = [node==0]
      for (int i2 = tid; i2 < 16 * HH; i2 += 512) {
        int m = i2 >> 7, k = i2 & 127;
        c0L[m * SP + k] = 0.f; h0L[m * SP + k] = 0.f;
        c1L[m * SP + k] = 0.f; h1L[m * SP + k] = 0.f;
      }
      if (tid < 16) ipL[tid] = (((row0 + tid) & (NN - 1)) == 0) ? 1.0f : 0.0f;
    }
    if (!lstmLive) continue;  // block-uniform
    __syncthreads();          // prologue state visible

    // pristine exit-row copy (before LSTM overwrites)
    if (exm >= 0 && exm < 16 && tid < 128) {
      exitP[tid] = c0L[exm * SP + tid];
      exitP[128 + tid] = h0L[exm * SP + tid];
      exitP[256 + tid] = c1L[exm * SP + tid];
      exitP[384 + tid] = h1L[exm * SP + tid];
    }
    // c-state into registers; build bf16 h A-fragments
    float c0r[4], c1r[4], h0r[4], h1r[4];
#pragma unroll
    for (int r = 0; r < 4; ++r) {
      int m = qq * 4 + r;
      c0r[r] = c0L[m * SP + kcol];
      c1r[r] = c1L[m * SP + kcol];
      h0r[r] = h0L[m * SP + kcol];
      h1r[r] = h1L[m * SP + kcol];
      hA0[basePos + m * 8] = f2bu(h0r[r]);
      hA1[basePos + m * 8] = f2bu(h1r[r]);
    }
    __syncthreads();  // fragments ready

    for (int t = 0; t < TT; ++t) {
      // read old-h fragments + layer-0 D-init from vocab table
      s16x8 a0[4], a1b[4];
#pragma unroll
      for (int kb = 0; kb < 4; ++kb) { a0[kb] = hA0v[kb * 64 + lane]; a1b[kb] = hA1v[kb * 64 + lane]; }
      f32x4 d0[4];
#pragma unroll
      for (int g = 0; g < 4; ++g) {
        int colz = (w + 8 * g) * 16 + n16;
#pragma unroll
        for (int r = 0; r < 4; ++r)
          d0[g][r] = tab[(size_t)toks[(qq * 4 + r) * 4 + t] * CC + colz];
      }
      __syncthreads();  // all frag reads done before overwrites

      // layer 0 MFMA: z = tab(+b0) + h0 @ Wh0
#pragma unroll
      for (int g = 0; g < 4; ++g)
#pragma unroll
        for (int kb = 0; kb < 4; ++kb)
          d0[g] = __builtin_amdgcn_mfma_f32_16x16x32_bf16(a0[kb], B0f[g][kb], d0[g], 0, 0, 0);

      // gates 0 in registers
#pragma unroll
      for (int r = 0; r < 4; ++r) {
        float cn = sigf(d0[1][r]) * c0r[r] + sigf(d0[0][r]) * tanhr(d0[2][r]);
        float hn = sigf(d0[3][r]) * tanhr(cn);
        c0r[r] = cn; h0r[r] = hn;
        hA0[basePos + (qq * 4 + r) * 8] = f2bu(hn);
      }
      __syncthreads();  // h0_new fragments visible

      // layer 1 MFMA: z = b1 + h0new @ Wi1 + h1old @ Wh1
      s16x8 a1a[4];
#pragma unroll
      for (int kb = 0; kb < 4; ++kb) a1a[kb] = hA0v[kb * 64 + lane];
      f32x4 d1[4];
#pragma unroll
      for (int g = 0; g < 4; ++g) {
        int ci = w + 8 * g;
        s16x8 wi[4];
#pragma unroll
        for (int kb = 0; kb < 4; ++kb) wi[kb] = pWi1[(ci * 4 + kb) * 64 + lane];
        f32x4 d = { b1v[g], b1v[g], b1v[g], b1v[g] };
#pragma unroll
        for (int kb = 0; kb < 4; ++kb)
          d = __builtin_amdgcn_mfma_f32_16x16x32_bf16(a1a[kb], wi[kb], d, 0, 0, 0);
#pragma unroll
        for (int kb = 0; kb < 4; ++kb)
          d = __builtin_amdgcn_mfma_f32_16x16x32_bf16(a1b[kb], B1f[g][kb], d, 0, 0, 0);
        d1[g] = d;
      }

      // gates 1 in registers
#pragma unroll
      for (int r = 0; r < 4; ++r) {
        float cn = sigf(d1[1][r]) * c1r[r] + sigf(d1[0][r]) * tanhr(d1[2][r]);
        float hn = sigf(d1[3][r]) * tanhr(cn);
        c1r[r] = cn; h1r[r] = hn;
        hA1[basePos + (qq * 4 + r) * 8] = f2bu(hn);
      }
      __syncthreads();  // h1_new fragments visible for next token
    }

    // epilogue: final states regs -> LDS
#pragma unroll
    for (int r = 0; r < 4; ++r) {
      int m = qq * 4 + r;
      c0L[m * SP + kcol] = c0r[r];
      h0L[m * SP + kcol] = h0r[r];
      c1L[m * SP + kcol] = c1r[r];
      h1L[m * SP + kcol] = h1r[r];
    }
    __syncthreads();

    // fused branch softmax (32 threads per row); exit row uses pristine copy
    {
      const int m = tid >> 5, sub = tid & 31;
      const int row = row0 + m;
      const bool isExit = (m == exm);
      float z0 = 0.f, z1 = 0.f;
#pragma unroll
      for (int u = 0; u < 16; ++u) {
        int k = u * 32 + sub;
        int seg = k >> 7, kk = k & 127;
        float fk;
        if (isExit) {
          fk = exitP[seg * 128 + kk];
        } else {
          fk = (seg == 0) ? c0L[m * SP + kk] : (seg == 1) ? h0L[m * SP + kk]
             : (seg == 2) ? c1L[m * SP + kk] : h1L[m * SP + kk];
        }
        z0 += fk * Wb[2 * k];
        z1 += fk * Wb[2 * k + 1];
      }
#pragma unroll
      for (int off = 16; off >= 1; off >>= 1) {
        z0 += __shfl_xor(z0, off);
        z1 += __shfl_xor(z1, off);
      }
      if (sub == 0) {
        z0 += bbp[0]; z1 += bbp[1];
        float mx = fmaxf(z0, z1);
        float e0 = __expf(z0 - mx), e1 = __expf(z1 - mx);
        float inv = 1.0f / (e0 + e1);
        float ipv = ipL[m];
        wtWp[row] = e0 * inv * ipv;
        wfWp[row] = e1 * inv * ipv;
      }
    }

    // writeout working state; exit row from pristine copy
    for (int s2 = tid; s2 < 16 * HH; s2 += 512) {
      int m = s2 >> 7, k = s2 & 127;
      bool ex = (m == exm);
      size_t g = (size_t)(row0 + m) * HH + k;
      Ww0[g] = ex ? exitP[k] : c0L[m * SP + k];
      Ww1[g] = ex ? exitP[128 + k] : h0L[m * SP + k];
      Ww2[g] = ex ? exitP[256 + k] : c1L[m * SP + k];
      Ww3[g] = ex ? exitP[384 + k] : h1L[m * SP + k];
    }
  }

  grid.sync();

  // ================= final logits (blocks 0..31: 2 blocks/batch, 1 output/thread) =====
  if (blk < 32) {
    const int fb2 = blk >> 1;
    float* f = exitP;
    f[tid] = fin[fb2 * 512 + tid];
    __syncthreads();
    int v = (blk & 1) * 512 + tid;
    if (v < OUTV) {
      float acc = bo[v];
#pragma unroll 8
      for (int k = 0; k < 512; ++k) acc += f[k] * Wo[(size_t)k * OUTV + v];
      out[fb2 * OUTV + v] = acc;
    }
  }
}

// distinct failure signature if workspace too small: out := 0 -> err == ref absmax
__global__ void zero_out_kernel(float* __restrict__ out, int n) {
  int i = blockIdx.x * blockDim.x + threadIdx.x;
  if (i < n) out[i] = 0.0f;
}

// ---------------- host orchestration ----------------

extern "C" void kernel_launch(void* const* d_in, const int* in_sizes, int n_in,
                              void* d_out, int out_size, void* d_ws, size_t ws_size,
                              hipStream_t stream) {
  const int* data = (const int*)d_in[0];
  const int* tb   = (const int*)d_in[1];
  const int* fb   = (const int*)d_in[2];
  const int* exi  = (const int*)d_in[3];
  const int* steps = (const int*)d_in[4];
  const float* embed = (const float*)d_in[5];
  const float* Wi = (const float*)d_in[6];
  const float* Wh = (const float*)d_in[7];
  const float* bl = (const float*)d_in[8];
  const float* Wb = (const float*)d_in[9];
  const float* bbp = (const float*)d_in[10];
  const float* Wo = (const float*)d_in[11];
  const float* bo = (const float*)d_in[12];
  float* out = (float*)d_out;
  float* ws = (float*)d_ws;
  (void)in_sizes; (void)n_in; (void)out_size;

  // required workspace (f32 units)
  size_t need = (size_t)1024 * CC          // tab
              + 8 * (size_t)SSZ            // WA + WB
              + 3 * 32768                  // swz (bf16)
              + 4 * MM                     // wt/wf x2
              + (MM + 16) + 2 * MM         // offs + edges (ints)
              + 16 * 512;                  // fin
  if (ws_size < need * sizeof(float)) {
    zero_out_kernel<<<(BB * OUTV + 255) / 256, 256, 0, stream>>>(out, BB * OUTV);
    return;
  }

  void* kargs[] = { (void*)&data, (void*)&tb, (void*)&fb, (void*)&exi, (void*)&steps,
                    (void*)&embed, (void*)&Wi, (void*)&Wh, (void*)&bl, (void*)&Wb,
                    (void*)&bbp, (void*)&Wo, (void*)&bo, (void*)&out, (void*)&ws };
  hipLaunchCooperativeKernel((const void*)mega_kernel, dim3(256), dim3(512),
                             kargs, 0, stream);
}

// Round 9
// 1045.599 us; speedup vs baseline: 1.2652x; 1.2652x over previous
//
#include <hip/hip_runtime.h>
#include <hip/hip_cooperative_groups.h>
#include <hip/hip_bf16.h>
#include <stdint.h>
#include <stddef.h>

namespace cg = cooperative_groups;

static constexpr int BB = 16, NN = 256, TT = 4, HH = 128;
static constexpr int MM = BB * NN;     // 4096 rows
static constexpr int CC = 512;         // 4*H gate width
static constexpr int OUTV = 1000;
static constexpr int SP = 132;         // f32 state row pitch in LDS

typedef float f32x4 __attribute__((ext_vector_type(4)));
typedef short s16x8 __attribute__((ext_vector_type(8)));

__device__ __forceinline__ float sigf(float x) { return 1.0f / (1.0f + __expf(-x)); }
__device__ __forceinline__ float tanhr(float x) { return 2.0f / (1.0f + __expf(-2.0f * x)) - 1.0f; }
__device__ __forceinline__ unsigned short f2bu(float a) {
  return __builtin_bit_cast(unsigned short, __float2bfloat16(a));
}
__device__ __forceinline__ unsigned int packh(float a, float b) {
  return (unsigned int)f2bu(a) | ((unsigned int)f2bu(b) << 16);
}
__device__ __forceinline__ float blo(unsigned int u) { return __builtin_bit_cast(float, u << 16); }
__device__ __forceinline__ float bhi(unsigned int u) { return __builtin_bit_cast(float, u & 0xffff0000u); }

// agent-scope coherent (coherence-point) accesses — no cache-invalidating fences needed
__device__ __forceinline__ float gldf(const float* p) {
  return __hip_atomic_load(p, __ATOMIC_RELAXED, __HIP_MEMORY_SCOPE_AGENT);
}
__device__ __forceinline__ unsigned int gldu(const unsigned int* p) {
  return __hip_atomic_load(p, __ATOMIC_RELAXED, __HIP_MEMORY_SCOPE_AGENT);
}
__device__ __forceinline__ void gstf(float* p, float v) {
  __hip_atomic_store(p, v, __ATOMIC_RELAXED, __HIP_MEMORY_SCOPE_AGENT);
}
__device__ __forceinline__ void gstu(unsigned int* p, unsigned int v) {
  __hip_atomic_store(p, v, __ATOMIC_RELAXED, __HIP_MEMORY_SCOPE_AGENT);
}

// One persistent cooperative kernel. 256 blocks x 512 threads; block owns 16 rows.
// ONE grid.sync after setup (read-only data stays L2-hot forever after).
// Step loop uses PER-BATCH barriers (16-block fan-in, monotonic counter, relaxed
// agent atomics); all cross-step state moves via agent-scope atomics (c f32, h bf16).
__global__ __launch_bounds__(512, 2) void mega_kernel(
    const int* __restrict__ data, const int* __restrict__ tb, const int* __restrict__ fb,
    const int* __restrict__ exi, const int* __restrict__ steps,
    const float* __restrict__ embed, const float* __restrict__ Wi, const float* __restrict__ Wh,
    const float* __restrict__ bl, const float* __restrict__ Wb, const float* __restrict__ bbp,
    const float* __restrict__ Wo, const float* __restrict__ bo,
    float* __restrict__ out, float* __restrict__ ws) {
  cg::grid_group grid = cg::this_grid();
  const int blk = blockIdx.x;   // 0..255
  const int tid = threadIdx.x;  // 0..511

  // ---- workspace carve ----
  float* tab = ws;                                   // 1024*CC f32
  float* C0A = tab + (size_t)1024 * CC;              // MM*HH f32 each
  float* C1A = C0A + (size_t)MM * HH;
  float* C0B = C1A + (size_t)MM * HH;
  float* C1B = C0B + (size_t)MM * HH;
  unsigned int* H0A = (unsigned int*)(C1B + (size_t)MM * HH);  // MM*64 u32 each
  unsigned int* H1A = H0A + (size_t)MM * 64;
  unsigned int* H0B = H1A + (size_t)MM * 64;
  unsigned int* H1B = H0B + (size_t)MM * 64;
  unsigned short* swz = (unsigned short*)(H1B + (size_t)MM * 64);  // 3*65536 bf16
  float* wtwf = (float*)(swz + 3 * 65536);           // wtA,wfA,wtB,wfB
  int* offs = (int*)(wtwf + 4 * MM);                 // MM+16
  int* edges = offs + MM + 16;                       // 2*MM
  int* bar = edges + 2 * MM;                         // 16 counters, stride 16

  const float* Wi0 = Wi;
  const float* Wi1 = Wi + HH * CC;
  const float* Wh0 = Wh;
  const float* Wh1 = Wh + HH * CC;
  const float* b0 = bl;
  const float* b1 = bl + CC;
  unsigned short* swzWh0 = swz;
  unsigned short* swzWi1 = swz + 65536;
  unsigned short* swzWh1 = swz + 2 * 65536;
  float* wtA = wtwf;          float* wfA = wtwf + MM;
  float* wtB = wtwf + 2 * MM; float* wfB = wtwf + 3 * MM;

  __shared__ float c0L[16 * SP], h0L[16 * SP], c1L[16 * SP], h1L[16 * SP];
  __shared__ __align__(16) unsigned short hA0[2048], hA1[2048];
  __shared__ float exitP[512];
  __shared__ float ipL[16];
  __shared__ int toks[64];

  // ================= setup =================
  for (int i = blk * 512 + tid; i < 3 * 65536; i += 256 * 512) {
    int mtx = i >> 16, ii = i & 65535;
    const float* W = (mtx == 0) ? Wh0 : (mtx == 1) ? Wi1 : Wh1;
    int j = ii & 7, ln = (ii >> 3) & 63, kb = (ii >> 9) & 3, ct = ii >> 11;
    int n = ln & 15, q = ln >> 4;
    swz[i] = f2bu(W[(kb * 32 + q * 8 + j) * CC + ct * 16 + n]);
  }
  if (blk < 16) {  // per-batch CSR, block-local in LDS
    int* cnt = (int*)h0L;
    int* sc = cnt + 256;
    int* cur = cnt + 512;
    if (tid < 256) cnt[tid] = 0;
    __syncthreads();
    const int n = tid >> 1, bit = tid & 1;
    const int tgt = bit ? fb[blk * NN + n] : tb[blk * NN + n];
    atomicAdd(&cnt[tgt], 1);
    __syncthreads();
    if (tid < 256) sc[tid] = cnt[tid];
    __syncthreads();
    for (int ofs = 1; ofs < 256; ofs <<= 1) {
      int t2 = (tid < 256 && tid >= ofs) ? sc[tid - ofs] : 0;
      __syncthreads();
      if (tid < 256) sc[tid] += t2;
      __syncthreads();
    }
    if (tid < 256) { offs[blk * NN + tid] = blk * 2 * NN + sc[tid] - cnt[tid]; cur[tid] = 0; }
    if (blk == 0 && tid == 0) offs[MM] = 2 * MM;
    __syncthreads();
    int lpos = sc[tgt] - cnt[tgt] + atomicAdd(&cur[tgt], 1);
    edges[blk * 2 * NN + lpos] = (n << 1) | bit;
  }
  if (blk == 16 && tid < 16) bar[tid * 16] = 0;  // zero per-batch barrier counters
  if (blk < 250) {  // XW0 vocab table: tab[v] = embed[v]@Wi0 + b0
    float* A = c0L;
    const int v0 = blk * 4;
    A[tid] = embed[(size_t)(v0 + (tid >> 7)) * HH + (tid & 127)];
    __syncthreads();
    const int j = tid;
    float a0 = b0[j], a1 = a0, a2 = a0, a3 = a0;
#pragma unroll 4
    for (int k = 0; k < HH; ++k) {
      float wv = Wi0[k * CC + j];
      a0 += A[k] * wv; a1 += A[128 + k] * wv; a2 += A[256 + k] * wv; a3 += A[384 + k] * wv;
    }
    tab[(size_t)v0 * CC + j] = a0;
    tab[(size_t)(v0 + 1) * CC + j] = a1;
    tab[(size_t)(v0 + 2) * CC + j] = a2;
    tab[(size_t)(v0 + 3) * CC + j] = a3;
  }
  if (tid < 64) toks[tid] = data[(blk * 16 + (tid >> 2)) * TT + (tid & 3)];

  grid.sync();  // the ONLY grid-wide fence; read-only data stays cached after this

  // ================= per-block constants =================
  const int row0 = blk * 16;
  const int b = row0 >> 8;
  const int sb = steps[b];
  const int exnode = exi[b];
  const int exm = exnode - (row0 & (NN - 1));
  const bool ownExit = (exm >= 0 && exm < 16);
  const int w = tid >> 6, lane = tid & 63;
  const int n16 = lane & 15, qq = lane >> 4;
  const int kcol = w * 16 + n16;
  const int basePos = ((kcol >> 5) * 64 + ((kcol >> 3) & 3) * 16) * 8 + (kcol & 7);

  const s16x8* pWh0 = (const s16x8*)swzWh0;
  const s16x8* pWh1 = (const s16x8*)swzWh1;
  const s16x8* pWi1 = (const s16x8*)swzWi1;
  s16x8 B0f[4][4], B1f[4][4];
  float b1v[4];
#pragma unroll
  for (int g = 0; g < 4; ++g) {
    int ci = w + 8 * g;
#pragma unroll
    for (int kb = 0; kb < 4; ++kb) {
      B0f[g][kb] = pWh0[(ci * 4 + kb) * 64 + lane];
      B1f[g][kb] = pWh1[(ci * 4 + kb) * 64 + lane];
    }
    b1v[g] = b1[ci * 16 + n16];
  }
  const s16x8* hA0v = (const s16x8*)hA0;
  const s16x8* hA1v = (const s16x8*)hA1;

  // ================= per-batch step loop =================
  for (int s = 0;; ++s) {
    const bool isFinal = (s == sb);
    if (isFinal && !ownExit) break;  // block-uniform

    if (s > 0) {  // wait until all 16 blocks of this batch finished writing step s-1
      if (tid == 0) {
        const int target = 16 * s;
        int it = 0;
        while (__hip_atomic_load(&bar[b * 16], __ATOMIC_RELAXED, __HIP_MEMORY_SCOPE_AGENT) < target) {
          if (++it > 2000000) break;  // safety: never hang
          __builtin_amdgcn_s_sleep(8);
        }
      }
      __syncthreads();
    }

    const int ps = s & 1;
    float* C0w = ps ? C0B : C0A;              float* C1w = ps ? C1B : C1A;
    unsigned int* H0w = ps ? H0B : H0A;       unsigned int* H1w = ps ? H1B : H1A;
    const float* C0r = ps ? C0A : C0B;        const float* C1r = ps ? C1A : C1B;
    const unsigned int* H0r = ps ? H0A : H0B; const unsigned int* H1r = ps ? H1A : H1B;
    float* wtW = ps ? wtB : wtA;              float* wfW = ps ? wfB : wfA;
    const float* wtR = ps ? wtA : wtB;        const float* wfR = ps ? wfA : wfB;

    if (s == 0) {
      for (int i2 = tid; i2 < 16 * HH; i2 += 512) {
        int m = i2 >> 7, k = i2 & 127;
        c0L[m * SP + k] = 0.f; h0L[m * SP + k] = 0.f;
        c1L[m * SP + k] = 0.f; h1L[m * SP + k] = 0.f;
      }
      if (tid < 16) ipL[tid] = (((row0 + tid) & (NN - 1)) == 0) ? 1.0f : 0.0f;
    } else {
      // ----- agg prologue: gather step s-1 state via agent-scope loads
      const int l = tid & 31;
      const int m = tid >> 5;
      const int node = row0 + m;
      const int beg = offs[node], end = offs[node + 1];
      float ac0[4] = {0, 0, 0, 0}, ac1[4] = {0, 0, 0, 0};
      float ah0[4] = {0, 0, 0, 0}, ah1[4] = {0, 0, 0, 0};
      float wsum = 0.f;
      for (int e = beg; e < end; ++e) {
        int rec = edges[e];
        int src = (b << 8) + (rec >> 1);
        float wv = gldf((rec & 1) ? &wfR[src] : &wtR[src]);
        wsum += wv;
        const float* pc0 = C0r + (size_t)src * HH + 4 * l;
        const float* pc1 = C1r + (size_t)src * HH + 4 * l;
        const unsigned int* ph0 = H0r + (size_t)src * 64 + 2 * l;
        const unsigned int* ph1 = H1r + (size_t)src * 64 + 2 * l;
        float c00 = gldf(pc0), c01 = gldf(pc0 + 1), c02 = gldf(pc0 + 2), c03 = gldf(pc0 + 3);
        float c10 = gldf(pc1), c11 = gldf(pc1 + 1), c12 = gldf(pc1 + 2), c13 = gldf(pc1 + 3);
        unsigned int u00 = gldu(ph0), u01 = gldu(ph0 + 1);
        unsigned int u10 = gldu(ph1), u11 = gldu(ph1 + 1);
        ac0[0] += wv * c00; ac0[1] += wv * c01; ac0[2] += wv * c02; ac0[3] += wv * c03;
        ac1[0] += wv * c10; ac1[1] += wv * c11; ac1[2] += wv * c12; ac1[3] += wv * c13;
        ah0[0] += wv * blo(u00); ah0[1] += wv * bhi(u00);
        ah0[2] += wv * blo(u01); ah0[3] += wv * bhi(u01);
        ah1[0] += wv * blo(u10); ah1[1] += wv * bhi(u10);
        ah1[2] += wv * blo(u11); ah1[3] += wv * bhi(u11);
      }
      float inv = 1.0f / (wsum + 1e-7f);
#pragma unroll
      for (int i = 0; i < 4; ++i) {
        int k = 4 * l + i;
        c0L[m * SP + k] = ac0[i] * inv;
        c1L[m * SP + k] = ac1[i] * inv;
        h0L[m * SP + k] = ah0[i] * inv;
        h1L[m * SP + k] = ah1[i] * inv;
      }
      if (l == 0) ipL[m] = wsum;
    }
    __syncthreads();  // prologue state visible

    if (isFinal) {
      // ----- final logits for this batch (exit-owner block only)
      if (tid < 128) {
        exitP[tid] = c0L[exm * SP + tid];
        exitP[128 + tid] = h0L[exm * SP + tid];
        exitP[256 + tid] = c1L[exm * SP + tid];
        exitP[384 + tid] = h1L[exm * SP + tid];
      }
      __syncthreads();
#pragma unroll
      for (int half = 0; half < 2; ++half) {
        int v = half * 512 + tid;
        if (v < OUTV) {
          float acc = bo[v];
#pragma unroll 8
          for (int k = 0; k < 512; ++k) acc += exitP[k] * Wo[(size_t)k * OUTV + v];
          out[b * OUTV + v] = acc;
        }
      }
      break;
    }

    // pristine exit-row copy
    if (ownExit && tid < 128) {
      exitP[tid] = c0L[exm * SP + tid];
      exitP[128 + tid] = h0L[exm * SP + tid];
      exitP[256 + tid] = c1L[exm * SP + tid];
      exitP[384 + tid] = h1L[exm * SP + tid];
    }
    // c-state into registers; bf16 h A-fragments
    float c0r[4], c1r[4], h0r[4], h1r[4];
#pragma unroll
    for (int r = 0; r < 4; ++r) {
      int m = qq * 4 + r;
      c0r[r] = c0L[m * SP + kcol];
      c1r[r] = c1L[m * SP + kcol];
      h0r[r] = h0L[m * SP + kcol];
      h1r[r] = h1L[m * SP + kcol];
      hA0[basePos + m * 8] = f2bu(h0r[r]);
      hA1[basePos + m * 8] = f2bu(h1r[r]);
    }
    __syncthreads();  // fragments ready

    for (int t = 0; t < TT; ++t) {
      s16x8 a0[4], a1b[4];
#pragma unroll
      for (int kb = 0; kb < 4; ++kb) { a0[kb] = hA0v[kb * 64 + lane]; a1b[kb] = hA1v[kb * 64 + lane]; }
      f32x4 d0[4];
#pragma unroll
      for (int g = 0; g < 4; ++g) {
        int colz = (w + 8 * g) * 16 + n16;
#pragma unroll
        for (int r = 0; r < 4; ++r)
          d0[g][r] = tab[(size_t)toks[(qq * 4 + r) * 4 + t] * CC + colz];
      }
      __syncthreads();  // frag reads done before overwrites

#pragma unroll
      for (int g = 0; g < 4; ++g)
#pragma unroll
        for (int kb = 0; kb < 4; ++kb)
          d0[g] = __builtin_amdgcn_mfma_f32_16x16x32_bf16(a0[kb], B0f[g][kb], d0[g], 0, 0, 0);

#pragma unroll
      for (int r = 0; r < 4; ++r) {
        float cn = sigf(d0[1][r]) * c0r[r] + sigf(d0[0][r]) * tanhr(d0[2][r]);
        float hn = sigf(d0[3][r]) * tanhr(cn);
        c0r[r] = cn; h0r[r] = hn;
        hA0[basePos + (qq * 4 + r) * 8] = f2bu(hn);
      }
      __syncthreads();  // h0_new fragments visible

      s16x8 a1a[4];
#pragma unroll
      for (int kb = 0; kb < 4; ++kb) a1a[kb] = hA0v[kb * 64 + lane];
      f32x4 d1[4];
#pragma unroll
      for (int g = 0; g < 4; ++g) {
        int ci = w + 8 * g;
        s16x8 wi[4];
#pragma unroll
        for (int kb = 0; kb < 4; ++kb) wi[kb] = pWi1[(ci * 4 + kb) * 64 + lane];
        f32x4 d = { b1v[g], b1v[g], b1v[g], b1v[g] };
#pragma unroll
        for (int kb = 0; kb < 4; ++kb)
          d = __builtin_amdgcn_mfma_f32_16x16x32_bf16(a1a[kb], wi[kb], d, 0, 0, 0);
#pragma unroll
        for (int kb = 0; kb < 4; ++kb)
          d = __builtin_amdgcn_mfma_f32_16x16x32_bf16(a1b[kb], B1f[g][kb], d, 0, 0, 0);
        d1[g] = d;
      }

#pragma unroll
      for (int r = 0; r < 4; ++r) {
        float cn = sigf(d1[1][r]) * c1r[r] + sigf(d1[0][r]) * tanhr(d1[2][r]);
        float hn = sigf(d1[3][r]) * tanhr(cn);
        c1r[r] = cn; h1r[r] = hn;
        hA1[basePos + (qq * 4 + r) * 8] = f2bu(hn);
      }
      __syncthreads();  // h1_new fragments visible
    }

    // epilogue: regs -> LDS
#pragma unroll
    for (int r = 0; r < 4; ++r) {
      int m = qq * 4 + r;
      c0L[m * SP + kcol] = c0r[r];
      h0L[m * SP + kcol] = h0r[r];
      c1L[m * SP + kcol] = c1r[r];
      h1L[m * SP + kcol] = h1r[r];
    }
    __syncthreads();

    // branch softmax (32 threads/row); exit row uses pristine copy
    {
      const int m = tid >> 5, sub = tid & 31;
      const int row = row0 + m;
      const bool isExit = (m == exm);
      float z0 = 0.f, z1 = 0.f;
#pragma unroll
      for (int u = 0; u < 16; ++u) {
        int k = u * 32 + sub;
        int seg = k >> 7, kk = k & 127;
        float fk;
        if (isExit) {
          fk = exitP[seg * 128 + kk];
        } else {
          fk = (seg == 0) ? c0L[m * SP + kk] : (seg == 1) ? h0L[m * SP + kk]
             : (seg == 2) ? c1L[m * SP + kk] : h1L[m * SP + kk];
        }
        z0 += fk * Wb[2 * k];
        z1 += fk * Wb[2 * k + 1];
      }
#pragma unroll
      for (int off = 16; off >= 1; off >>= 1) {
        z0 += __shfl_xor(z0, off);
        z1 += __shfl_xor(z1, off);
      }
      if (sub == 0) {
        z0 += bbp[0]; z1 += bbp[1];
        float mx = fmaxf(z0, z1);
        float e0 = __expf(z0 - mx), e1 = __expf(z1 - mx);
        float inv = 1.0f / (e0 + e1);
        float ipv = ipL[m];
        gstf(&wtW[row], e0 * inv * ipv);
        gstf(&wfW[row], e1 * inv * ipv);
      }
    }

    // writeout (agent-scope stores); exit row from pristine copy
    {
      const int m = tid >> 5, l = tid & 31;
      const bool ex = (m == exm);
      const int grow = row0 + m;
#pragma unroll
      for (int i = 0; i < 4; ++i) {
        int k = 4 * l + i;
        gstf(&C0w[(size_t)grow * HH + k], ex ? exitP[k] : c0L[m * SP + k]);
        gstf(&C1w[(size_t)grow * HH + k], ex ? exitP[256 + k] : c1L[m * SP + k]);
      }
#pragma unroll
      for (int jj = 0; jj < 2; ++jj) {
        int k0 = 4 * l + 2 * jj;
        float h0a = ex ? exitP[128 + k0] : h0L[m * SP + k0];
        float h0b = ex ? exitP[128 + k0 + 1] : h0L[m * SP + k0 + 1];
        float h1a = ex ? exitP[384 + k0] : h1L[m * SP + k0];
        float h1b = ex ? exitP[384 + k0 + 1] : h1L[m * SP + k0 + 1];
        gstu(&H0w[(size_t)grow * 64 + 2 * l + jj], packh(h0a, h0b));
        gstu(&H1w[(size_t)grow * 64 + 2 * l + jj], packh(h1a, h1b));
      }
    }
    __syncthreads();  // drains each wave's vmcnt before the arrive
    if (tid == 0)
      __hip_atomic_fetch_add(&bar[b * 16], 1, __ATOMIC_RELAXED, __HIP_MEMORY_SCOPE_AGENT);
  }
}

// distinct failure signature if workspace too small: out := 0 -> err == ref absmax
__global__ void zero_out_kernel(float* __restrict__ out, int n) {
  int i = blockIdx.x * blockDim.x + threadIdx.x;
  if (i < n) out[i] = 0.0f;
}

// ---------------- host orchestration ----------------

extern "C" void kernel_launch(void* const* d_in, const int* in_sizes, int n_in,
                              void* d_out, int out_size, void* d_ws, size_t ws_size,
                              hipStream_t stream) {
  const int* data = (const int*)d_in[0];
  const int* tb   = (const int*)d_in[1];
  const int* fb   = (const int*)d_in[2];
  const int* exi  = (const int*)d_in[3];
  const int* steps = (const int*)d_in[4];
  const float* embed = (const float*)d_in[5];
  const float* Wi = (const float*)d_in[6];
  const float* Wh = (const float*)d_in[7];
  const float* bl = (const float*)d_in[8];
  const float* Wb = (const float*)d_in[9];
  const float* bbp = (const float*)d_in[10];
  const float* Wo = (const float*)d_in[11];
  const float* bo = (const float*)d_in[12];
  float* out = (float*)d_out;
  float* ws = (float*)d_ws;
  (void)in_sizes; (void)n_in; (void)out_size;

  // required workspace (f32 units)
  size_t need = (size_t)1024 * CC            // tab
              + 4 * (size_t)MM * HH          // C0A,C1A,C0B,C1B
              + 2 * (size_t)MM * 64          // H0A/H1A + H0B/H1B (u32, = MM*64 each x4 halves)
              + (size_t)MM * 64 * 2          // (total 4 x MM*64 u32 = 2*MM*128 f32-units) [conservative]
              + 3 * 32768                    // swz bf16
              + 4 * MM                       // wt/wf x2
              + (MM + 16) + 2 * MM           // offs + edges
              + 256 + 64;                    // bar + pad
  if (ws_size < need * sizeof(float)) {
    zero_out_kernel<<<(BB * OUTV + 255) / 256, 256, 0, stream>>>(out, BB * OUTV);
    return;
  }

  void* kargs[] = { (void*)&data, (void*)&tb, (void*)&fb, (void*)&exi, (void*)&steps,
                    (void*)&embed, (void*)&Wi, (void*)&Wh, (void*)&bl, (void*)&Wb,
                    (void*)&bbp, (void*)&Wo, (void*)&bo, (void*)&out, (void*)&ws };
  hipLaunchCooperativeKernel((const void*)mega_kernel, dim3(256), dim3(512),
                             kargs, 0, stream);
}

// Round 10
// 578.378 us; speedup vs baseline: 2.2872x; 1.8078x over previous
//
#include <hip/hip_runtime.h>
#include <hip/hip_bf16.h>
#include <stdint.h>
#include <stddef.h>

static constexpr int BB = 16, NN = 256, TT = 4, HH = 128;
static constexpr int MM = BB * NN;     // 4096 rows
static constexpr int CC = 512;         // 4*H gate width
static constexpr int OUTV = 1000;
static constexpr int MAXS = 15;
static constexpr int SP = 132;         // f32 state row pitch in LDS

typedef float f32x4 __attribute__((ext_vector_type(4)));
typedef short s16x8 __attribute__((ext_vector_type(8)));

__device__ __forceinline__ float sigf(float x) { return 1.0f / (1.0f + __expf(-x)); }
__device__ __forceinline__ float tanhr(float x) { return 2.0f / (1.0f + __expf(-2.0f * x)) - 1.0f; }
__device__ __forceinline__ unsigned short f2bu(float a) {
  return __builtin_bit_cast(unsigned short, __float2bfloat16(a));
}
__device__ __forceinline__ unsigned int packh(float a, float b) {
  return (unsigned int)f2bu(a) | ((unsigned int)f2bu(b) << 16);
}
__device__ __forceinline__ float blo(unsigned int u) { return __builtin_bit_cast(float, u << 16); }
__device__ __forceinline__ float bhi(unsigned int u) { return __builtin_bit_cast(float, u & 0xffff0000u); }

// ---------------- setup kernels ----------------

__global__ void init_kernel(int* __restrict__ count) {
  int i = blockIdx.x * 256 + threadIdx.x;
  if (i < MM) count[i] = 0;
}

// all three weight matrices -> bf16 B-fragment order in one launch
__global__ void swz_all_kernel(const float* __restrict__ Wh0, const float* __restrict__ Wi1,
                               const float* __restrict__ Wh1, unsigned short* __restrict__ swz) {
  int i = blockIdx.x * 256 + threadIdx.x;  // 0..196607
  int mtx = i >> 16, ii = i & 65535;
  const float* W = (mtx == 0) ? Wh0 : (mtx == 1) ? Wi1 : Wh1;
  int j = ii & 7, ln = (ii >> 3) & 63, kb = (ii >> 9) & 3, ct = ii >> 11;
  int n = ln & 15, q = ln >> 4;
  swz[i] = f2bu(W[(kb * 32 + q * 8 + j) * CC + ct * 16 + n]);
}

// tab[v][col] = embed[v] @ Wi0 + b0
__global__ void xw0tab_kernel(const float* __restrict__ embed, const float* __restrict__ Wi0,
                              const float* __restrict__ b0, float* __restrict__ tab) {
  const int v0 = blockIdx.x * 8;
  const int j = threadIdx.x;  // 256
  __shared__ float A[8][HH];
  for (int s = j; s < 8 * HH; s += 256) {
    int r = s >> 7, k = s & 127;
    int v = v0 + r; if (v >= OUTV) v = OUTV - 1;
    A[r][k] = embed[(size_t)v * HH + k];
  }
  __syncthreads();
  float za[8], zb[8];
  {
    float ba = b0[j], bbv = b0[j + 256];
#pragma unroll
    for (int r = 0; r < 8; ++r) { za[r] = ba; zb[r] = bbv; }
  }
#pragma unroll 4
  for (int k = 0; k < HH; ++k) {
    float wa = Wi0[k * CC + j], wb = Wi0[k * CC + j + 256];
#pragma unroll
    for (int r = 0; r < 8; ++r) { za[r] += A[r][k] * wa; zb[r] += A[r][k] * wb; }
  }
#pragma unroll
  for (int r = 0; r < 8; ++r) {
    tab[(size_t)(v0 + r) * CC + j] = za[r];
    tab[(size_t)(v0 + r) * CC + j + 256] = zb[r];
  }
}

__global__ void edge_count(const int* __restrict__ tb, const int* __restrict__ fb,
                           int* __restrict__ count) {
  int e = blockIdx.x * blockDim.x + threadIdx.x;
  if (e >= 2 * MM) return;
  int b = e >> 9, r = e & 511, n = r >> 1, bit = r & 1;
  int tgt = bit ? fb[b * NN + n] : tb[b * NN + n];
  atomicAdd(&count[b * NN + tgt], 1);
}

__global__ void edge_scan(int* __restrict__ count, int* __restrict__ offs) {
  int b = blockIdx.x, tid = threadIdx.x;
  __shared__ int s[256];
  int v = count[b * NN + tid];
  s[tid] = v;
  __syncthreads();
  for (int off = 1; off < 256; off <<= 1) {
    int t = (tid >= off) ? s[tid - off] : 0;
    __syncthreads();
    s[tid] += t;
    __syncthreads();
  }
  offs[b * NN + tid] = b * 2 * NN + s[tid] - v;
  count[b * NN + tid] = 0;  // reuse as fill cursor
  if (b == 0 && tid == 0) offs[MM] = 2 * MM;
}

__global__ void edge_fill(const int* __restrict__ tb, const int* __restrict__ fb,
                          const int* __restrict__ offs, int* __restrict__ cursor,
                          int* __restrict__ edges) {
  int e = blockIdx.x * blockDim.x + threadIdx.x;
  if (e >= 2 * MM) return;
  int b = e >> 9, r = e & 511, n = r >> 1, bit = r & 1;
  int tgt = bit ? fb[b * NN + n] : tb[b * NN + n];
  int pos = offs[b * NN + tgt] + atomicAdd(&cursor[b * NN + tgt], 1);
  edges[pos] = (n << 1) | bit;
}

// ---------------- fused per-step kernel ----------------
// 16 rows/block, 512 threads = 8 waves; agg prologue + 4 tokens x 2 layers LSTM (MFMA,
// gates in D registers) + branch softmax + writeout. Cross-step state is PACKED bf16:
// row layout = 32 lane-groups x 8 u32: [c0x4 | h0x4 | c1x4 | h1x4] for lane's 4 columns
// -> one edge gather = 2 x dwordx4 per lane (1 KB/row vs 2 KB f32). c/h stay f32 inside
// the step; only the once-per-step cross-block handoff rounds to bf16.

__global__ __launch_bounds__(512, 2) void step_kernel(
    float* __restrict__ Sc0g, float* __restrict__ Sh0g,
    float* __restrict__ Sc1g, float* __restrict__ Sh1g,
    const unsigned int* __restrict__ Pr, unsigned int* __restrict__ Pw,
    const float* __restrict__ wtR, const float* __restrict__ wfR,
    float* __restrict__ wtW, float* __restrict__ wfW,
    const int* __restrict__ offs, const int* __restrict__ edges,
    const float* __restrict__ tab,
    const unsigned short* __restrict__ swzWh0, const unsigned short* __restrict__ swzWi1,
    const unsigned short* __restrict__ swzWh1, const float* __restrict__ b1,
    const float* __restrict__ Wb, const float* __restrict__ bb,
    const int* __restrict__ data, const int* __restrict__ exi,
    const int* __restrict__ steps, int step) {
  const int row0 = blockIdx.x * 16;
  const int b = row0 >> 8;
  const int sb = steps[b];
  const bool aggLive = (step >= 1) && ((step - 1) < sb);
  const bool lstmLive = (step < sb);
  if (!aggLive && !lstmLive) return;

  const int tid = threadIdx.x;
  const int w = tid >> 6;
  const int lane = tid & 63;
  const int n16 = lane & 15, qq = lane >> 4;
  const int kcol = w * 16 + n16;
  const int basePos = ((kcol >> 5) * 64 + ((kcol >> 3) & 3) * 16) * 8 + (kcol & 7);

  __shared__ float c0L[16 * SP], h0L[16 * SP], c1L[16 * SP], h1L[16 * SP];
  __shared__ __align__(16) unsigned short hA0[2048], hA1[2048];
  __shared__ float exitP[512];
  __shared__ float ipL[16];
  __shared__ int toks[64];

  // ----- prologue: aggregate previous step (16 nodes, 32 lanes each)
  if (aggLive) {
    const int l = tid & 31;
    const int m = tid >> 5;
    const int node = row0 + m;
    const int beg = offs[node], end = offs[node + 1];
    float ac0[4] = {0,0,0,0}, ah0[4] = {0,0,0,0}, ac1[4] = {0,0,0,0}, ah1[4] = {0,0,0,0};
    float wsum = 0.f;
    for (int e = beg; e < end; ++e) {
      int rec = edges[e];
      int src = (b << 8) + (rec >> 1);
      float wv = (rec & 1) ? wfR[src] : wtR[src];
      wsum += wv;
      const uint4* pr = (const uint4*)(Pr + (size_t)src * 256 + 8 * l);
      uint4 u0 = pr[0], u1 = pr[1];
      ac0[0] += wv * blo(u0.x); ac0[1] += wv * bhi(u0.x);
      ac0[2] += wv * blo(u0.y); ac0[3] += wv * bhi(u0.y);
      ah0[0] += wv * blo(u0.z); ah0[1] += wv * bhi(u0.z);
      ah0[2] += wv * blo(u0.w); ah0[3] += wv * bhi(u0.w);
      ac1[0] += wv * blo(u1.x); ac1[1] += wv * bhi(u1.x);
      ac1[2] += wv * blo(u1.y); ac1[3] += wv * bhi(u1.y);
      ah1[0] += wv * blo(u1.z); ah1[1] += wv * bhi(u1.z);
      ah1[2] += wv * blo(u1.w); ah1[3] += wv * bhi(u1.w);
    }
    float inv = 1.0f / (wsum + 1e-7f);
    float4 o0 = { ac0[0]*inv, ac0[1]*inv, ac0[2]*inv, ac0[3]*inv };
    float4 o1 = { ah0[0]*inv, ah0[1]*inv, ah0[2]*inv, ah0[3]*inv };
    float4 o2 = { ac1[0]*inv, ac1[1]*inv, ac1[2]*inv, ac1[3]*inv };
    float4 o3 = { ah1[0]*inv, ah1[1]*inv, ah1[2]*inv, ah1[3]*inv };
    ((float4*)c0L)[m * (SP / 4) + l] = o0;
    ((float4*)h0L)[m * (SP / 4) + l] = o1;
    ((float4*)c1L)[m * (SP / 4) + l] = o2;
    ((float4*)h1L)[m * (SP / 4) + l] = o3;
    if (l == 0) ipL[m] = wsum;
    if (!lstmLive) {  // batch death: persist exact f32 state for final_kernel
      ((float4*)Sc0g)[node * 32 + l] = o0;
      ((float4*)Sh0g)[node * 32 + l] = o1;
      ((float4*)Sc1g)[node * 32 + l] = o2;
      ((float4*)Sh1g)[node * 32 + l] = o3;
    }
  } else {
    // step 0: zero states, initial ip = [node==0]
    for (int i2 = tid; i2 < 16 * HH; i2 += 512) {
      int m = i2 >> 7, k = i2 & 127;
      c0L[m * SP + k] = 0.f; h0L[m * SP + k] = 0.f;
      c1L[m * SP + k] = 0.f; h1L[m * SP + k] = 0.f;
    }
    if (tid < 16) ipL[tid] = (((row0 + tid) & (NN - 1)) == 0) ? 1.0f : 0.0f;
  }
  if (!lstmLive) return;  // block-uniform

  // persistent B fragments: Wh0, Wh1, tiles ci = w + 8g
  s16x8 B0f[4][4], B1f[4][4];
  const s16x8* pWh0 = (const s16x8*)swzWh0;
  const s16x8* pWh1 = (const s16x8*)swzWh1;
  const s16x8* pWi1 = (const s16x8*)swzWi1;
  float b1v[4];
#pragma unroll
  for (int g = 0; g < 4; ++g) {
    int ci = w + 8 * g;
#pragma unroll
    for (int kb = 0; kb < 4; ++kb) {
      B0f[g][kb] = pWh0[(ci * 4 + kb) * 64 + lane];
      B1f[g][kb] = pWh1[(ci * 4 + kb) * 64 + lane];
    }
    b1v[g] = b1[ci * 16 + n16];
  }

  const int exnode = exi[b];
  const int exm = exnode - (row0 & (NN - 1));
  if (tid < 64) toks[tid] = data[(row0 + (tid >> 2)) * TT + (tid & 3)];
  __syncthreads();  // prologue state visible

  // pristine exit-row copy
  if (exm >= 0 && exm < 16 && tid < 128) {
    exitP[tid] = c0L[exm * SP + tid];
    exitP[128 + tid] = h0L[exm * SP + tid];
    exitP[256 + tid] = c1L[exm * SP + tid];
    exitP[384 + tid] = h1L[exm * SP + tid];
  }

  // c-state into registers; build bf16 h A-fragments
  float c0r[4], c1r[4], h0r[4], h1r[4];
#pragma unroll
  for (int r = 0; r < 4; ++r) {
    int m = qq * 4 + r;
    c0r[r] = c0L[m * SP + kcol];
    c1r[r] = c1L[m * SP + kcol];
    h0r[r] = h0L[m * SP + kcol];
    h1r[r] = h1L[m * SP + kcol];
    hA0[basePos + m * 8] = f2bu(h0r[r]);
    hA1[basePos + m * 8] = f2bu(h1r[r]);
  }
  __syncthreads();  // fragments ready

  const s16x8* hA0v = (const s16x8*)hA0;
  const s16x8* hA1v = (const s16x8*)hA1;

  for (int t = 0; t < TT; ++t) {
    s16x8 a0[4], a1b[4];
#pragma unroll
    for (int kb = 0; kb < 4; ++kb) { a0[kb] = hA0v[kb * 64 + lane]; a1b[kb] = hA1v[kb * 64 + lane]; }
    f32x4 d0[4];
#pragma unroll
    for (int g = 0; g < 4; ++g) {
      int colz = (w + 8 * g) * 16 + n16;
#pragma unroll
      for (int r = 0; r < 4; ++r)
        d0[g][r] = tab[(size_t)toks[(qq * 4 + r) * 4 + t] * CC + colz];
    }
    __syncthreads();  // frag reads done before overwrites

    // layer 0 MFMA: z = tab(+b0) + h0 @ Wh0
#pragma unroll
    for (int g = 0; g < 4; ++g)
#pragma unroll
      for (int kb = 0; kb < 4; ++kb)
        d0[g] = __builtin_amdgcn_mfma_f32_16x16x32_bf16(a0[kb], B0f[g][kb], d0[g], 0, 0, 0);

    // gates 0 in registers
#pragma unroll
    for (int r = 0; r < 4; ++r) {
      float cn = sigf(d0[1][r]) * c0r[r] + sigf(d0[0][r]) * tanhr(d0[2][r]);
      float hn = sigf(d0[3][r]) * tanhr(cn);
      c0r[r] = cn; h0r[r] = hn;
      hA0[basePos + (qq * 4 + r) * 8] = f2bu(hn);
    }
    __syncthreads();  // h0_new fragments visible

    // layer 1 MFMA: z = b1 + h0new @ Wi1 + h1old @ Wh1
    s16x8 a1a[4];
#pragma unroll
    for (int kb = 0; kb < 4; ++kb) a1a[kb] = hA0v[kb * 64 + lane];
    f32x4 d1[4];
#pragma unroll
    for (int g = 0; g < 4; ++g) {
      int ci = w + 8 * g;
      s16x8 wi[4];
#pragma unroll
      for (int kb = 0; kb < 4; ++kb) wi[kb] = pWi1[(ci * 4 + kb) * 64 + lane];
      f32x4 d = { b1v[g], b1v[g], b1v[g], b1v[g] };
#pragma unroll
      for (int kb = 0; kb < 4; ++kb)
        d = __builtin_amdgcn_mfma_f32_16x16x32_bf16(a1a[kb], wi[kb], d, 0, 0, 0);
#pragma unroll
      for (int kb = 0; kb < 4; ++kb)
        d = __builtin_amdgcn_mfma_f32_16x16x32_bf16(a1b[kb], B1f[g][kb], d, 0, 0, 0);
      d1[g] = d;
    }

    // gates 1 in registers
#pragma unroll
    for (int r = 0; r < 4; ++r) {
      float cn = sigf(d1[1][r]) * c1r[r] + sigf(d1[0][r]) * tanhr(d1[2][r]);
      float hn = sigf(d1[3][r]) * tanhr(cn);
      c1r[r] = cn; h1r[r] = hn;
      hA1[basePos + (qq * 4 + r) * 8] = f2bu(hn);
    }
    __syncthreads();  // h1_new fragments visible
  }

  // epilogue: regs -> LDS
#pragma unroll
  for (int r = 0; r < 4; ++r) {
    int m = qq * 4 + r;
    c0L[m * SP + kcol] = c0r[r];
    h0L[m * SP + kcol] = h0r[r];
    c1L[m * SP + kcol] = c1r[r];
    h1L[m * SP + kcol] = h1r[r];
  }
  __syncthreads();

  // branch softmax (32 threads/row); exit row uses pristine copy
  {
    const int m = tid >> 5, sub = tid & 31;
    const int row = row0 + m;
    const bool isExit = (m == exm);
    float z0 = 0.f, z1 = 0.f;
#pragma unroll
    for (int u = 0; u < 16; ++u) {
      int k = u * 32 + sub;
      int seg = k >> 7, kk = k & 127;
      float fk;
      if (isExit) {
        fk = exitP[seg * 128 + kk];
      } else {
        fk = (seg == 0) ? c0L[m * SP + kk] : (seg == 1) ? h0L[m * SP + kk]
           : (seg == 2) ? c1L[m * SP + kk] : h1L[m * SP + kk];
      }
      z0 += fk * Wb[2 * k];
      z1 += fk * Wb[2 * k + 1];
    }
#pragma unroll
    for (int off = 16; off >= 1; off >>= 1) {
      z0 += __shfl_xor(z0, off);
      z1 += __shfl_xor(z1, off);
    }
    if (sub == 0) {
      z0 += bb[0]; z1 += bb[1];
      float mx = fmaxf(z0, z1);
      float e0 = __expf(z0 - mx), e1 = __expf(z1 - mx);
      float inv = 1.0f / (e0 + e1);
      float ipv = ipL[m];
      wtW[row] = e0 * inv * ipv;
      wfW[row] = e1 * inv * ipv;
    }
  }

  // writeout: pack to bf16, 2 x dwordx4 per lane; exit row from pristine copy
  {
    const int m = tid >> 5, l = tid & 31;
    const bool ex = (m == exm);
    const int grow = row0 + m;
    float f0[4], f1[4], f2[4], f3[4];
#pragma unroll
    for (int i = 0; i < 4; ++i) {
      int k = 4 * l + i;
      f0[i] = ex ? exitP[k] : c0L[m * SP + k];
      f1[i] = ex ? exitP[128 + k] : h0L[m * SP + k];
      f2[i] = ex ? exitP[256 + k] : c1L[m * SP + k];
      f3[i] = ex ? exitP[384 + k] : h1L[m * SP + k];
    }
    uint4 o0 = { packh(f0[0], f0[1]), packh(f0[2], f0[3]),
                 packh(f1[0], f1[1]), packh(f1[2], f1[3]) };
    uint4 o1 = { packh(f2[0], f2[1]), packh(f2[2], f2[3]),
                 packh(f3[0], f3[1]), packh(f3[2], f3[3]) };
    uint4* pw = (uint4*)(Pw + (size_t)grow * 256 + 8 * l);
    pw[0] = o0; pw[1] = o1;
  }
}

// logits: 64 blocks (16 batches x 4 col-tiles of 250), 256 threads, 1 output/thread
__global__ void final_kernel(const float* __restrict__ Sc0, const float* __restrict__ Sh0,
                             const float* __restrict__ Sc1, const float* __restrict__ Sh1,
                             const int* __restrict__ exi, const float* __restrict__ Wo,
                             const float* __restrict__ bo, float* __restrict__ out) {
  const int b = blockIdx.x >> 2;
  const int vt = blockIdx.x & 3;
  const int tid = threadIdx.x;  // 256
  __shared__ float f[512];
  int row = b * NN + exi[b];
  if (tid < 128) {
    size_t g = (size_t)row * HH + tid;
    f[tid] = Sc0[g];
    f[128 + tid] = Sh0[g];
    f[256 + tid] = Sc1[g];
    f[384 + tid] = Sh1[g];
  }
  __syncthreads();
  if (tid < 250) {
    int v = vt * 250 + tid;
    float acc = bo[v];
#pragma unroll 8
    for (int k = 0; k < 512; ++k) acc += f[k] * Wo[(size_t)k * OUTV + v];
    out[b * OUTV + v] = acc;
  }
}

// distinct failure signature if workspace too small: out := 0 -> err == ref absmax
__global__ void zero_out_kernel(float* __restrict__ out, int n) {
  int i = blockIdx.x * blockDim.x + threadIdx.x;
  if (i < n) out[i] = 0.0f;
}

// ---------------- host orchestration ----------------

extern "C" void kernel_launch(void* const* d_in, const int* in_sizes, int n_in,
                              void* d_out, int out_size, void* d_ws, size_t ws_size,
                              hipStream_t stream) {
  const int* data = (const int*)d_in[0];
  const int* tb   = (const int*)d_in[1];
  const int* fb   = (const int*)d_in[2];
  const int* exi  = (const int*)d_in[3];
  const int* steps = (const int*)d_in[4];
  const float* embed = (const float*)d_in[5];
  const float* Wi = (const float*)d_in[6];   // (L,H,4H)
  const float* Wh = (const float*)d_in[7];   // (L,H,4H)
  const float* bl = (const float*)d_in[8];   // (L,4H)
  const float* Wb = (const float*)d_in[9];   // (2LH,2)
  const float* bb = (const float*)d_in[10];  // (2,)
  const float* Wo = (const float*)d_in[11];  // (2LH,OUT)
  const float* bo = (const float*)d_in[12];  // (OUT,)
  float* out = (float*)d_out;

  const float* Wi0 = Wi;
  const float* Wi1 = Wi + HH * CC;
  const float* Wh0 = Wh;
  const float* Wh1 = Wh + HH * CC;
  const float* b0 = bl;
  const float* b1 = bl + CC;

  float* ws = (float*)d_ws;
  size_t off = 0;
  float* tab = ws + off;  off += (size_t)1024 * CC;        // 2 MB
  float* Sc0 = ws + off;  off += (size_t)MM * HH;          // death/final f32 bufs
  float* Sh0 = ws + off;  off += (size_t)MM * HH;
  float* Sc1 = ws + off;  off += (size_t)MM * HH;
  float* Sh1 = ws + off;  off += (size_t)MM * HH;
  unsigned int* PA = (unsigned int*)(ws + off); off += (size_t)MM * 256;  // packed state A
  unsigned int* PB = (unsigned int*)(ws + off); off += (size_t)MM * 256;  // packed state B
  unsigned short* swz = (unsigned short*)(ws + off); off += 3 * 32768;    // 3x65536 bf16
  float* wtA = ws + off;  off += MM;
  float* wfA = ws + off;  off += MM;
  float* wtB = ws + off;  off += MM;
  float* wfB = ws + off;  off += MM;
  int* count = (int*)(ws + off); off += MM;
  int* offs  = (int*)(ws + off); off += MM + 16;
  int* edges = (int*)(ws + off); off += 2 * MM;
  (void)in_sizes; (void)n_in; (void)out_size;

  if (ws_size < off * sizeof(float)) {
    zero_out_kernel<<<(BB * OUTV + 255) / 256, 256, 0, stream>>>(out, BB * OUTV);
    return;
  }

  unsigned short* swzWh0 = swz;
  unsigned short* swzWi1 = swz + 65536;
  unsigned short* swzWh1 = swz + 2 * 65536;

  init_kernel<<<16, 256, 0, stream>>>(count);
  swz_all_kernel<<<768, 256, 0, stream>>>(Wh0, Wi1, Wh1, swz);
  xw0tab_kernel<<<128, 256, 0, stream>>>(embed, Wi0, b0, tab);
  edge_count<<<32, 256, 0, stream>>>(tb, fb, count);
  edge_scan<<<BB, 256, 0, stream>>>(count, offs);
  edge_fill<<<32, 256, 0, stream>>>(tb, fb, offs, count, edges);

  // dispatch s: prologue aggregates step s-1 (reads other parity), LSTM writes parity s&1.
  for (int s = 0; s <= MAXS; ++s) {
    unsigned int* Pwp = (s & 1) ? PB : PA;
    const unsigned int* Prp = (s & 1) ? PA : PB;
    float* wtWp = (s & 1) ? wtB : wtA;
    float* wfWp = (s & 1) ? wfB : wfA;
    const float* wtRp = (s & 1) ? wtA : wtB;
    const float* wfRp = (s & 1) ? wfA : wfB;
    step_kernel<<<MM / 16, 512, 0, stream>>>(
        Sc0, Sh0, Sc1, Sh1, Prp, Pwp,
        wtRp, wfRp, wtWp, wfWp,
        offs, edges, tab, swzWh0, swzWi1, swzWh1, b1, Wb, bb,
        data, exi, steps, s);
  }
  final_kernel<<<BB * 4, 256, 0, stream>>>(Sc0, Sh0, Sc1, Sh1, exi, Wo, bo, out);
}

// Round 11
// 559.722 us; speedup vs baseline: 2.3634x; 1.0333x over previous
//
#include <hip/hip_runtime.h>
#include <hip/hip_bf16.h>
#include <stdint.h>
#include <stddef.h>

static constexpr int BB = 16, NN = 256, TT = 4, HH = 128;
static constexpr int MM = BB * NN;     // 4096 rows
static constexpr int CC = 512;         // 4*H gate width
static constexpr int OUTV = 1000;
static constexpr int MAXS = 15;
static constexpr int SP = 132;         // f32 state row pitch in LDS

typedef float f32x4 __attribute__((ext_vector_type(4)));
typedef short s16x8 __attribute__((ext_vector_type(8)));

__device__ __forceinline__ float sigf(float x) { return 1.0f / (1.0f + __expf(-x)); }
__device__ __forceinline__ float tanhr(float x) { return 2.0f / (1.0f + __expf(-2.0f * x)) - 1.0f; }
__device__ __forceinline__ unsigned short f2bu(float a) {
  return __builtin_bit_cast(unsigned short, __float2bfloat16(a));
}
__device__ __forceinline__ unsigned int packh(float a, float b) {
  return (unsigned int)f2bu(a) | ((unsigned int)f2bu(b) << 16);
}
__device__ __forceinline__ float blo(unsigned int u) { return __builtin_bit_cast(float, u << 16); }
__device__ __forceinline__ float bhi(unsigned int u) { return __builtin_bit_cast(float, u & 0xffff0000u); }

// ---------------- setup kernels ----------------

__global__ void init_kernel(int* __restrict__ count) {
  int i = blockIdx.x * 256 + threadIdx.x;
  if (i < MM) count[i] = 0;
}

// all three weight matrices -> bf16 B-fragment order in one launch
__global__ void swz_all_kernel(const float* __restrict__ Wh0, const float* __restrict__ Wi1,
                               const float* __restrict__ Wh1, unsigned short* __restrict__ swz) {
  int i = blockIdx.x * 256 + threadIdx.x;  // 0..196607
  int mtx = i >> 16, ii = i & 65535;
  const float* W = (mtx == 0) ? Wh0 : (mtx == 1) ? Wi1 : Wh1;
  int j = ii & 7, ln = (ii >> 3) & 63, kb = (ii >> 9) & 3, ct = ii >> 11;
  int n = ln & 15, q = ln >> 4;
  swz[i] = f2bu(W[(kb * 32 + q * 8 + j) * CC + ct * 16 + n]);
}

// tab[v][col] = embed[v] @ Wi0 + b0
__global__ void xw0tab_kernel(const float* __restrict__ embed, const float* __restrict__ Wi0,
                              const float* __restrict__ b0, float* __restrict__ tab) {
  const int v0 = blockIdx.x * 8;
  const int j = threadIdx.x;  // 256
  __shared__ float A[8][HH];
  for (int s = j; s < 8 * HH; s += 256) {
    int r = s >> 7, k = s & 127;
    int v = v0 + r; if (v >= OUTV) v = OUTV - 1;
    A[r][k] = embed[(size_t)v * HH + k];
  }
  __syncthreads();
  float za[8], zb[8];
  {
    float ba = b0[j], bbv = b0[j + 256];
#pragma unroll
    for (int r = 0; r < 8; ++r) { za[r] = ba; zb[r] = bbv; }
  }
#pragma unroll 4
  for (int k = 0; k < HH; ++k) {
    float wa = Wi0[k * CC + j], wb = Wi0[k * CC + j + 256];
#pragma unroll
    for (int r = 0; r < 8; ++r) { za[r] += A[r][k] * wa; zb[r] += A[r][k] * wb; }
  }
#pragma unroll
  for (int r = 0; r < 8; ++r) {
    tab[(size_t)(v0 + r) * CC + j] = za[r];
    tab[(size_t)(v0 + r) * CC + j + 256] = zb[r];
  }
}

__global__ void edge_count(const int* __restrict__ tb, const int* __restrict__ fb,
                           int* __restrict__ count) {
  int e = blockIdx.x * blockDim.x + threadIdx.x;
  if (e >= 2 * MM) return;
  int b = e >> 9, r = e & 511, n = r >> 1, bit = r & 1;
  int tgt = bit ? fb[b * NN + n] : tb[b * NN + n];
  atomicAdd(&count[b * NN + tgt], 1);
}

__global__ void edge_scan(int* __restrict__ count, int* __restrict__ offs) {
  int b = blockIdx.x, tid = threadIdx.x;
  __shared__ int s[256];
  int v = count[b * NN + tid];
  s[tid] = v;
  __syncthreads();
  for (int off = 1; off < 256; off <<= 1) {
    int t = (tid >= off) ? s[tid - off] : 0;
    __syncthreads();
    s[tid] += t;
    __syncthreads();
  }
  offs[b * NN + tid] = b * 2 * NN + s[tid] - v;
  count[b * NN + tid] = 0;  // reuse as fill cursor
  if (b == 0 && tid == 0) offs[MM] = 2 * MM;
}

__global__ void edge_fill(const int* __restrict__ tb, const int* __restrict__ fb,
                          const int* __restrict__ offs, int* __restrict__ cursor,
                          int* __restrict__ edges) {
  int e = blockIdx.x * blockDim.x + threadIdx.x;
  if (e >= 2 * MM) return;
  int b = e >> 9, r = e & 511, n = r >> 1, bit = r & 1;
  int tgt = bit ? fb[b * NN + n] : tb[b * NN + n];
  int pos = offs[b * NN + tgt] + atomicAdd(&cursor[b * NN + tgt], 1);
  edges[pos] = (n << 1) | bit;
}

// ---------------- fused per-step kernel ----------------
// 16 rows/block, 512 threads = 8 waves; agg prologue + 4 tokens x 2 layers LSTM (MFMA,
// gates in D registers) + branch softmax + writeout. Cross-step state is PACKED bf16.
//
// XCD-LOCAL BATCH MAPPING: HW dispatches blocks round-robin (XCD ~ blockIdx % 8).
// Remap so all 16 blocks of batch b satisfy blockIdx === b (mod 8): each batch is
// pinned to one XCD, so step s's state writes and step s+1's gathers for the same
// batch hit the SAME per-XCD L2 (which persists across dispatch boundaries) instead
// of round-tripping through L3. Pure perf heuristic; correctness unaffected.

__global__ __launch_bounds__(512, 2) void step_kernel(
    float* __restrict__ Sc0g, float* __restrict__ Sh0g,
    float* __restrict__ Sc1g, float* __restrict__ Sh1g,
    const unsigned int* __restrict__ Pr, unsigned int* __restrict__ Pw,
    const float* __restrict__ wtR, const float* __restrict__ wfR,
    float* __restrict__ wtW, float* __restrict__ wfW,
    const int* __restrict__ offs, const int* __restrict__ edges,
    const float* __restrict__ tab,
    const unsigned short* __restrict__ swzWh0, const unsigned short* __restrict__ swzWi1,
    const unsigned short* __restrict__ swzWh1, const float* __restrict__ b1,
    const float* __restrict__ Wb, const float* __restrict__ bb,
    const int* __restrict__ data, const int* __restrict__ exi,
    const int* __restrict__ steps, int step) {
  const int B = blockIdx.x;
  const int b = (B & 7) | (((B >> 3) & 1) << 3);  // batch, pinned to XCD b%8
  const int g16 = B >> 4;                          // node-group 0..15 within batch
  const int row0 = b * NN + g16 * 16;
  const int sb = steps[b];
  const bool aggLive = (step >= 1) && ((step - 1) < sb);
  const bool lstmLive = (step < sb);
  if (!aggLive && !lstmLive) return;

  const int tid = threadIdx.x;
  const int w = tid >> 6;
  const int lane = tid & 63;
  const int n16 = lane & 15, qq = lane >> 4;
  const int kcol = w * 16 + n16;
  const int basePos = ((kcol >> 5) * 64 + ((kcol >> 3) & 3) * 16) * 8 + (kcol & 7);

  __shared__ float c0L[16 * SP], h0L[16 * SP], c1L[16 * SP], h1L[16 * SP];
  __shared__ __align__(16) unsigned short hA0[2048], hA1[2048];
  __shared__ float exitP[512];
  __shared__ float ipL[16];
  __shared__ int toks[64];

  // ----- prologue: aggregate previous step (16 nodes, 32 lanes each)
  if (aggLive) {
    const int l = tid & 31;
    const int m = tid >> 5;
    const int node = row0 + m;
    const int beg = offs[node], end = offs[node + 1];
    float ac0[4] = {0,0,0,0}, ah0[4] = {0,0,0,0}, ac1[4] = {0,0,0,0}, ah1[4] = {0,0,0,0};
    float wsum = 0.f;
    for (int e = beg; e < end; ++e) {
      int rec = edges[e];
      int src = (b << 8) + (rec >> 1);
      float wv = (rec & 1) ? wfR[src] : wtR[src];
      wsum += wv;
      const uint4* pr = (const uint4*)(Pr + (size_t)src * 256 + 8 * l);
      uint4 u0 = pr[0], u1 = pr[1];
      ac0[0] += wv * blo(u0.x); ac0[1] += wv * bhi(u0.x);
      ac0[2] += wv * blo(u0.y); ac0[3] += wv * bhi(u0.y);
      ah0[0] += wv * blo(u0.z); ah0[1] += wv * bhi(u0.z);
      ah0[2] += wv * blo(u0.w); ah0[3] += wv * bhi(u0.w);
      ac1[0] += wv * blo(u1.x); ac1[1] += wv * bhi(u1.x);
      ac1[2] += wv * blo(u1.y); ac1[3] += wv * bhi(u1.y);
      ah1[0] += wv * blo(u1.z); ah1[1] += wv * bhi(u1.z);
      ah1[2] += wv * blo(u1.w); ah1[3] += wv * bhi(u1.w);
    }
    float inv = 1.0f / (wsum + 1e-7f);
    float4 o0 = { ac0[0]*inv, ac0[1]*inv, ac0[2]*inv, ac0[3]*inv };
    float4 o1 = { ah0[0]*inv, ah0[1]*inv, ah0[2]*inv, ah0[3]*inv };
    float4 o2 = { ac1[0]*inv, ac1[1]*inv, ac1[2]*inv, ac1[3]*inv };
    float4 o3 = { ah1[0]*inv, ah1[1]*inv, ah1[2]*inv, ah1[3]*inv };
    ((float4*)c0L)[m * (SP / 4) + l] = o0;
    ((float4*)h0L)[m * (SP / 4) + l] = o1;
    ((float4*)c1L)[m * (SP / 4) + l] = o2;
    ((float4*)h1L)[m * (SP / 4) + l] = o3;
    if (l == 0) ipL[m] = wsum;
    if (!lstmLive) {  // batch death: persist exact f32 state for final_kernel
      ((float4*)Sc0g)[node * 32 + l] = o0;
      ((float4*)Sh0g)[node * 32 + l] = o1;
      ((float4*)Sc1g)[node * 32 + l] = o2;
      ((float4*)Sh1g)[node * 32 + l] = o3;
    }
  } else {
    // step 0: zero states, initial ip = [node==0]
    for (int i2 = tid; i2 < 16 * HH; i2 += 512) {
      int m = i2 >> 7, k = i2 & 127;
      c0L[m * SP + k] = 0.f; h0L[m * SP + k] = 0.f;
      c1L[m * SP + k] = 0.f; h1L[m * SP + k] = 0.f;
    }
    if (tid < 16) ipL[tid] = (((row0 + tid) & (NN - 1)) == 0) ? 1.0f : 0.0f;
  }
  if (!lstmLive) return;  // block-uniform

  // persistent B fragments: Wh0, Wh1, tiles ci = w + 8g
  s16x8 B0f[4][4], B1f[4][4];
  const s16x8* pWh0 = (const s16x8*)swzWh0;
  const s16x8* pWh1 = (const s16x8*)swzWh1;
  const s16x8* pWi1 = (const s16x8*)swzWi1;
  float b1v[4];
#pragma unroll
  for (int g = 0; g < 4; ++g) {
    int ci = w + 8 * g;
#pragma unroll
    for (int kb = 0; kb < 4; ++kb) {
      B0f[g][kb] = pWh0[(ci * 4 + kb) * 64 + lane];
      B1f[g][kb] = pWh1[(ci * 4 + kb) * 64 + lane];
    }
    b1v[g] = b1[ci * 16 + n16];
  }

  const int exnode = exi[b];
  const int exm = exnode - (g16 * 16);
  if (tid < 64) toks[tid] = data[(row0 + (tid >> 2)) * TT + (tid & 3)];
  __syncthreads();  // prologue state visible

  // pristine exit-row copy
  if (exm >= 0 && exm < 16 && tid < 128) {
    exitP[tid] = c0L[exm * SP + tid];
    exitP[128 + tid] = h0L[exm * SP + tid];
    exitP[256 + tid] = c1L[exm * SP + tid];
    exitP[384 + tid] = h1L[exm * SP + tid];
  }

  // c-state into registers; build bf16 h A-fragments
  float c0r[4], c1r[4], h0r[4], h1r[4];
#pragma unroll
  for (int r = 0; r < 4; ++r) {
    int m = qq * 4 + r;
    c0r[r] = c0L[m * SP + kcol];
    c1r[r] = c1L[m * SP + kcol];
    h0r[r] = h0L[m * SP + kcol];
    h1r[r] = h1L[m * SP + kcol];
    hA0[basePos + m * 8] = f2bu(h0r[r]);
    hA1[basePos + m * 8] = f2bu(h1r[r]);
  }
  __syncthreads();  // fragments ready

  const s16x8* hA0v = (const s16x8*)hA0;
  const s16x8* hA1v = (const s16x8*)hA1;

  for (int t = 0; t < TT; ++t) {
    s16x8 a0[4], a1b[4];
#pragma unroll
    for (int kb = 0; kb < 4; ++kb) { a0[kb] = hA0v[kb * 64 + lane]; a1b[kb] = hA1v[kb * 64 + lane]; }
    f32x4 d0[4];
#pragma unroll
    for (int g = 0; g < 4; ++g) {
      int colz = (w + 8 * g) * 16 + n16;
#pragma unroll
      for (int r = 0; r < 4; ++r)
        d0[g][r] = tab[(size_t)toks[(qq * 4 + r) * 4 + t] * CC + colz];
    }
    __syncthreads();  // frag reads done before overwrites

    // layer 0 MFMA: z = tab(+b0) + h0 @ Wh0
#pragma unroll
    for (int g = 0; g < 4; ++g)
#pragma unroll
      for (int kb = 0; kb < 4; ++kb)
        d0[g] = __builtin_amdgcn_mfma_f32_16x16x32_bf16(a0[kb], B0f[g][kb], d0[g], 0, 0, 0);

    // gates 0 in registers
#pragma unroll
    for (int r = 0; r < 4; ++r) {
      float cn = sigf(d0[1][r]) * c0r[r] + sigf(d0[0][r]) * tanhr(d0[2][r]);
      float hn = sigf(d0[3][r]) * tanhr(cn);
      c0r[r] = cn; h0r[r] = hn;
      hA0[basePos + (qq * 4 + r) * 8] = f2bu(hn);
    }
    __syncthreads();  // h0_new fragments visible

    // layer 1 MFMA: z = b1 + h0new @ Wi1 + h1old @ Wh1
    s16x8 a1a[4];
#pragma unroll
    for (int kb = 0; kb < 4; ++kb) a1a[kb] = hA0v[kb * 64 + lane];
    f32x4 d1[4];
#pragma unroll
    for (int g = 0; g < 4; ++g) {
      int ci = w + 8 * g;
      s16x8 wi[4];
#pragma unroll
      for (int kb = 0; kb < 4; ++kb) wi[kb] = pWi1[(ci * 4 + kb) * 64 + lane];
      f32x4 d = { b1v[g], b1v[g], b1v[g], b1v[g] };
#pragma unroll
      for (int kb = 0; kb < 4; ++kb)
        d = __builtin_amdgcn_mfma_f32_16x16x32_bf16(a1a[kb], wi[kb], d, 0, 0, 0);
#pragma unroll
      for (int kb = 0; kb < 4; ++kb)
        d = __builtin_amdgcn_mfma_f32_16x16x32_bf16(a1b[kb], B1f[g][kb], d, 0, 0, 0);
      d1[g] = d;
    }

    // gates 1 in registers
#pragma unroll
    for (int r = 0; r < 4; ++r) {
      float cn = sigf(d1[1][r]) * c1r[r] + sigf(d1[0][r]) * tanhr(d1[2][r]);
      float hn = sigf(d1[3][r]) * tanhr(cn);
      c1r[r] = cn; h1r[r] = hn;
      hA1[basePos + (qq * 4 + r) * 8] = f2bu(hn);
    }
    __syncthreads();  // h1_new fragments visible
  }

  // epilogue: regs -> LDS
#pragma unroll
  for (int r = 0; r < 4; ++r) {
    int m = qq * 4 + r;
    c0L[m * SP + kcol] = c0r[r];
    h0L[m * SP + kcol] = h0r[r];
    c1L[m * SP + kcol] = c1r[r];
    h1L[m * SP + kcol] = h1r[r];
  }
  __syncthreads();

  // branch softmax (32 threads/row); exit row uses pristine copy
  {
    const int m = tid >> 5, sub = tid & 31;
    const int row = row0 + m;
    const bool isExit = (m == exm);
    float z0 = 0.f, z1 = 0.f;
#pragma unroll
    for (int u = 0; u < 16; ++u) {
      int k = u * 32 + sub;
      int seg = k >> 7, kk = k & 127;
      float fk;
      if (isExit) {
        fk = exitP[seg * 128 + kk];
      } else {
        fk = (seg == 0) ? c0L[m * SP + kk] : (seg == 1) ? h0L[m * SP + kk]
           : (seg == 2) ? c1L[m * SP + kk] : h1L[m * SP + kk];
      }
      z0 += fk * Wb[2 * k];
      z1 += fk * Wb[2 * k + 1];
    }
#pragma unroll
    for (int off = 16; off >= 1; off >>= 1) {
      z0 += __shfl_xor(z0, off);
      z1 += __shfl_xor(z1, off);
    }
    if (sub == 0) {
      z0 += bb[0]; z1 += bb[1];
      float mx = fmaxf(z0, z1);
      float e0 = __expf(z0 - mx), e1 = __expf(z1 - mx);
      float inv = 1.0f / (e0 + e1);
      float ipv = ipL[m];
      wtW[row] = e0 * inv * ipv;
      wfW[row] = e1 * inv * ipv;
    }
  }

  // writeout: pack to bf16, 2 x dwordx4 per lane; exit row from pristine copy
  {
    const int m = tid >> 5, l = tid & 31;
    const bool ex = (m == exm);
    const int grow = row0 + m;
    float f0[4], f1[4], f2[4], f3[4];
#pragma unroll
    for (int i = 0; i < 4; ++i) {
      int k = 4 * l + i;
      f0[i] = ex ? exitP[k] : c0L[m * SP + k];
      f1[i] = ex ? exitP[128 + k] : h0L[m * SP + k];
      f2[i] = ex ? exitP[256 + k] : c1L[m * SP + k];
      f3[i] = ex ? exitP[384 + k] : h1L[m * SP + k];
    }
    uint4 o0 = { packh(f0[0], f0[1]), packh(f0[2], f0[3]),
                 packh(f1[0], f1[1]), packh(f1[2], f1[3]) };
    uint4 o1 = { packh(f2[0], f2[1]), packh(f2[2], f2[3]),
                 packh(f3[0], f3[1]), packh(f3[2], f3[3]) };
    uint4* pw = (uint4*)(Pw + (size_t)grow * 256 + 8 * l);
    pw[0] = o0; pw[1] = o1;
  }
}

// logits: 64 blocks (16 batches x 4 col-tiles of 250), 256 threads, 1 output/thread
__global__ void final_kernel(const float* __restrict__ Sc0, const float* __restrict__ Sh0,
                             const float* __restrict__ Sc1, const float* __restrict__ Sh1,
                             const int* __restrict__ exi, const float* __restrict__ Wo,
                             const float* __restrict__ bo, float* __restrict__ out) {
  const int b = blockIdx.x >> 2;
  const int vt = blockIdx.x & 3;
  const int tid = threadIdx.x;  // 256
  __shared__ float f[512];
  int row = b * NN + exi[b];
  if (tid < 128) {
    size_t g = (size_t)row * HH + tid;
    f[tid] = Sc0[g];
    f[128 + tid] = Sh0[g];
    f[256 + tid] = Sc1[g];
    f[384 + tid] = Sh1[g];
  }
  __syncthreads();
  if (tid < 250) {
    int v = vt * 250 + tid;
    float acc = bo[v];
#pragma unroll 8
    for (int k = 0; k < 512; ++k) acc += f[k] * Wo[(size_t)k * OUTV + v];
    out[b * OUTV + v] = acc;
  }
}

// distinct failure signature if workspace too small: out := 0 -> err == ref absmax
__global__ void zero_out_kernel(float* __restrict__ out, int n) {
  int i = blockIdx.x * blockDim.x + threadIdx.x;
  if (i < n) out[i] = 0.0f;
}

// ---------------- host orchestration ----------------

extern "C" void kernel_launch(void* const* d_in, const int* in_sizes, int n_in,
                              void* d_out, int out_size, void* d_ws, size_t ws_size,
                              hipStream_t stream) {
  const int* data = (const int*)d_in[0];
  const int* tb   = (const int*)d_in[1];
  const int* fb   = (const int*)d_in[2];
  const int* exi  = (const int*)d_in[3];
  const int* steps = (const int*)d_in[4];
  const float* embed = (const float*)d_in[5];
  const float* Wi = (const float*)d_in[6];   // (L,H,4H)
  const float* Wh = (const float*)d_in[7];   // (L,H,4H)
  const float* bl = (const float*)d_in[8];   // (L,4H)
  const float* Wb = (const float*)d_in[9];   // (2LH,2)
  const float* bb = (const float*)d_in[10];  // (2,)
  const float* Wo = (const float*)d_in[11];  // (2LH,OUT)
  const float* bo = (const float*)d_in[12];  // (OUT,)
  float* out = (float*)d_out;

  const float* Wi0 = Wi;
  const float* Wi1 = Wi + HH * CC;
  const float* Wh0 = Wh;
  const float* Wh1 = Wh + HH * CC;
  const float* b0 = bl;
  const float* b1 = bl + CC;

  float* ws = (float*)d_ws;
  size_t off = 0;
  float* tab = ws + off;  off += (size_t)1024 * CC;        // 2 MB
  float* Sc0 = ws + off;  off += (size_t)MM * HH;          // death/final f32 bufs
  float* Sh0 = ws + off;  off += (size_t)MM * HH;
  float* Sc1 = ws + off;  off += (size_t)MM * HH;
  float* Sh1 = ws + off;  off += (size_t)MM * HH;
  unsigned int* PA = (unsigned int*)(ws + off); off += (size_t)MM * 256;  // packed state A
  unsigned int* PB = (unsigned int*)(ws + off); off += (size_t)MM * 256;  // packed state B
  unsigned short* swz = (unsigned short*)(ws + off); off += 3 * 32768;    // 3x65536 bf16
  float* wtA = ws + off;  off += MM;
  float* wfA = ws + off;  off += MM;
  float* wtB = ws + off;  off += MM;
  float* wfB = ws + off;  off += MM;
  int* count = (int*)(ws + off); off += MM;
  int* offs  = (int*)(ws + off); off += MM + 16;
  int* edges = (int*)(ws + off); off += 2 * MM;
  (void)in_sizes; (void)n_in; (void)out_size;

  if (ws_size < off * sizeof(float)) {
    zero_out_kernel<<<(BB * OUTV + 255) / 256, 256, 0, stream>>>(out, BB * OUTV);
    return;
  }

  unsigned short* swzWh0 = swz;
  unsigned short* swzWi1 = swz + 65536;
  unsigned short* swzWh1 = swz + 2 * 65536;

  init_kernel<<<16, 256, 0, stream>>>(count);
  swz_all_kernel<<<768, 256, 0, stream>>>(Wh0, Wi1, Wh1, swz);
  xw0tab_kernel<<<128, 256, 0, stream>>>(embed, Wi0, b0, tab);
  edge_count<<<32, 256, 0, stream>>>(tb, fb, count);
  edge_scan<<<BB, 256, 0, stream>>>(count, offs);
  edge_fill<<<32, 256, 0, stream>>>(tb, fb, offs, count, edges);

  // dispatch s: prologue aggregates step s-1 (reads other parity), LSTM writes parity s&1.
  for (int s = 0; s <= MAXS; ++s) {
    unsigned int* Pwp = (s & 1) ? PB : PA;
    const unsigned int* Prp = (s & 1) ? PA : PB;
    float* wtWp = (s & 1) ? wtB : wtA;
    float* wfWp = (s & 1) ? wfB : wfA;
    const float* wtRp = (s & 1) ? wtA : wtB;
    const float* wfRp = (s & 1) ? wfA : wfB;
    step_kernel<<<MM / 16, 512, 0, stream>>>(
        Sc0, Sh0, Sc1, Sh1, Prp, Pwp,
        wtRp, wfRp, wtWp, wfWp,
        offs, edges, tab, swzWh0, swzWi1, swzWh1, b1, Wb, bb,
        data, exi, steps, s);
  }
  final_kernel<<<BB * 4, 256, 0, stream>>>(Sc0, Sh0, Sc1, Sh1, exi, Wo, bo, out);
}

// Round 12
// 551.073 us; speedup vs baseline: 2.4005x; 1.0157x over previous
//
#include <hip/hip_runtime.h>
#include <hip/hip_bf16.h>
#include <stdint.h>
#include <stddef.h>

static constexpr int BB = 16, NN = 256, TT = 4, HH = 128;
static constexpr int MM = BB * NN;     // 4096 rows
static constexpr int CC = 512;         // 4*H gate width
static constexpr int OUTV = 1000;
static constexpr int MAXS = 15;
static constexpr int SP = 132;         // f32 state row pitch in LDS

typedef float f32x4 __attribute__((ext_vector_type(4)));
typedef short s16x8 __attribute__((ext_vector_type(8)));

__device__ __forceinline__ float sigf(float x) { return 1.0f / (1.0f + __expf(-x)); }
__device__ __forceinline__ float tanhr(float x) { return 2.0f / (1.0f + __expf(-2.0f * x)) - 1.0f; }
__device__ __forceinline__ unsigned short f2bu(float a) {
  return __builtin_bit_cast(unsigned short, __float2bfloat16(a));
}
__device__ __forceinline__ unsigned int packh(float a, float b) {
  return (unsigned int)f2bu(a) | ((unsigned int)f2bu(b) << 16);
}
__device__ __forceinline__ float blo(unsigned int u) { return __builtin_bit_cast(float, u << 16); }
__device__ __forceinline__ float bhi(unsigned int u) { return __builtin_bit_cast(float, u & 0xffff0000u); }

// ---------------- setup kernels (2 dispatches total) ----------------

// per-batch CSR built entirely block-locally in LDS: 16 blocks x 512 threads
__global__ __launch_bounds__(512) void csr_kernel(const int* __restrict__ tb,
                                                  const int* __restrict__ fb,
                                                  int* __restrict__ offs,
                                                  int* __restrict__ edges) {
  const int blk = blockIdx.x;   // batch
  const int tid = threadIdx.x;  // 0..511 (one edge per thread)
  __shared__ int cnt[256], sc[256], cur[256];
  if (tid < 256) cnt[tid] = 0;
  __syncthreads();
  const int n = tid >> 1, bit = tid & 1;
  const int tgt = bit ? fb[blk * NN + n] : tb[blk * NN + n];
  atomicAdd(&cnt[tgt], 1);
  __syncthreads();
  if (tid < 256) sc[tid] = cnt[tid];
  __syncthreads();
  for (int ofs = 1; ofs < 256; ofs <<= 1) {
    int t2 = (tid < 256 && tid >= ofs) ? sc[tid - ofs] : 0;
    __syncthreads();
    if (tid < 256) sc[tid] += t2;
    __syncthreads();
  }
  if (tid < 256) { offs[blk * NN + tid] = blk * 2 * NN + sc[tid] - cnt[tid]; cur[tid] = 0; }
  if (blk == 0 && tid == 0) offs[MM] = 2 * MM;
  __syncthreads();
  int lpos = sc[tgt] - cnt[tgt] + atomicAdd(&cur[tgt], 1);
  edges[blk * 2 * NN + lpos] = (n << 1) | bit;
}

// blocks 0..767: weight swizzle -> bf16 B-fragment order; blocks 768..892: XW0 vocab table
__global__ __launch_bounds__(256) void prep_kernel(
    const float* __restrict__ Wh0, const float* __restrict__ Wi1, const float* __restrict__ Wh1,
    const float* __restrict__ embed, const float* __restrict__ Wi0, const float* __restrict__ b0,
    unsigned short* __restrict__ swz, float* __restrict__ tab) {
  const int blk = blockIdx.x;
  const int tid = threadIdx.x;
  if (blk < 768) {
    int i = blk * 256 + tid;  // 0..196607
    int mtx = i >> 16, ii = i & 65535;
    const float* W = (mtx == 0) ? Wh0 : (mtx == 1) ? Wi1 : Wh1;
    int j = ii & 7, ln = (ii >> 3) & 63, kb = (ii >> 9) & 3, ct = ii >> 11;
    int n = ln & 15, q = ln >> 4;
    swz[i] = f2bu(W[(kb * 32 + q * 8 + j) * CC + ct * 16 + n]);
    return;
  }
  // XW0: tab[v] = embed[v]@Wi0 + b0; 125 blocks x 8 rows = 1000 rows
  const int v0 = (blk - 768) * 8;
  __shared__ float A[8][HH];
  for (int s = tid; s < 8 * HH; s += 256) {
    int r = s >> 7, k = s & 127;
    A[r][k] = embed[(size_t)(v0 + r) * HH + k];
  }
  __syncthreads();
  const int j = tid;
  float za[8], zb[8];
  {
    float ba = b0[j], bbv = b0[j + 256];
#pragma unroll
    for (int r = 0; r < 8; ++r) { za[r] = ba; zb[r] = bbv; }
  }
#pragma unroll 4
  for (int k = 0; k < HH; ++k) {
    float wa = Wi0[k * CC + j], wb = Wi0[k * CC + j + 256];
#pragma unroll
    for (int r = 0; r < 8; ++r) { za[r] += A[r][k] * wa; zb[r] += A[r][k] * wb; }
  }
#pragma unroll
  for (int r = 0; r < 8; ++r) {
    tab[(size_t)(v0 + r) * CC + j] = za[r];
    tab[(size_t)(v0 + r) * CC + j + 256] = zb[r];
  }
}

// ---------------- fused per-step kernel ----------------
// 16 rows/block, 512 threads = 8 waves. XCD-pinned batches (blockIdx === b mod 8).
// Latency engineering: persistent B fragments loaded BEFORE the agg prologue (in
// flight during the gather); hA fragment buffers double-buffered -> 2 barriers/token.

__global__ __launch_bounds__(512) void step_kernel(
    float* __restrict__ Sc0g, float* __restrict__ Sh0g,
    float* __restrict__ Sc1g, float* __restrict__ Sh1g,
    const unsigned int* __restrict__ Pr, unsigned int* __restrict__ Pw,
    const float* __restrict__ wtR, const float* __restrict__ wfR,
    float* __restrict__ wtW, float* __restrict__ wfW,
    const int* __restrict__ offs, const int* __restrict__ edges,
    const float* __restrict__ tab,
    const unsigned short* __restrict__ swzWh0, const unsigned short* __restrict__ swzWi1,
    const unsigned short* __restrict__ swzWh1, const float* __restrict__ b1,
    const float* __restrict__ Wb, const float* __restrict__ bb,
    const int* __restrict__ data, const int* __restrict__ exi,
    const int* __restrict__ steps, int step) {
  const int B = blockIdx.x;
  const int b = (B & 7) | (((B >> 3) & 1) << 3);  // batch, pinned to XCD b%8
  const int g16 = B >> 4;                          // node-group 0..15 within batch
  const int row0 = b * NN + g16 * 16;
  const int sb = steps[b];
  const bool aggLive = (step >= 1) && ((step - 1) < sb);
  const bool lstmLive = (step < sb);
  if (!aggLive && !lstmLive) return;

  const int tid = threadIdx.x;
  const int w = tid >> 6;
  const int lane = tid & 63;
  const int n16 = lane & 15, qq = lane >> 4;
  const int kcol = w * 16 + n16;
  const int basePos = ((kcol >> 5) * 64 + ((kcol >> 3) & 3) * 16) * 8 + (kcol & 7);

  __shared__ float c0L[16 * SP], h0L[16 * SP], c1L[16 * SP], h1L[16 * SP];
  __shared__ __align__(16) unsigned short hA0[2][2048], hA1[2][2048];  // double-buffered
  __shared__ float exitP[512];
  __shared__ float ipL[16];
  __shared__ int toks[64];

  // ----- HOISTED persistent loads: issued before the gather so they overlap it
  s16x8 B0f[4][4], B1f[4][4];
  float b1v[4];
  const s16x8* pWh0 = (const s16x8*)swzWh0;
  const s16x8* pWh1 = (const s16x8*)swzWh1;
  const s16x8* pWi1 = (const s16x8*)swzWi1;
  if (lstmLive) {
#pragma unroll
    for (int g = 0; g < 4; ++g) {
      int ci = w + 8 * g;
#pragma unroll
      for (int kb = 0; kb < 4; ++kb) {
        B0f[g][kb] = pWh0[(ci * 4 + kb) * 64 + lane];
        B1f[g][kb] = pWh1[(ci * 4 + kb) * 64 + lane];
      }
      b1v[g] = b1[ci * 16 + n16];
    }
    if (tid < 64) toks[tid] = data[(row0 + (tid >> 2)) * TT + (tid & 3)];
  }

  // ----- prologue: aggregate previous step (16 nodes, 32 lanes each)
  if (aggLive) {
    const int l = tid & 31;
    const int m = tid >> 5;
    const int node = row0 + m;
    const int beg = offs[node], end = offs[node + 1];
    float ac0[4] = {0,0,0,0}, ah0[4] = {0,0,0,0}, ac1[4] = {0,0,0,0}, ah1[4] = {0,0,0,0};
    float wsum = 0.f;
    for (int e = beg; e < end; ++e) {
      int rec = edges[e];
      int src = (b << 8) + (rec >> 1);
      float wv = (rec & 1) ? wfR[src] : wtR[src];
      wsum += wv;
      const uint4* pr = (const uint4*)(Pr + (size_t)src * 256 + 8 * l);
      uint4 u0 = pr[0], u1 = pr[1];
      ac0[0] += wv * blo(u0.x); ac0[1] += wv * bhi(u0.x);
      ac0[2] += wv * blo(u0.y); ac0[3] += wv * bhi(u0.y);
      ah0[0] += wv * blo(u0.z); ah0[1] += wv * bhi(u0.z);
      ah0[2] += wv * blo(u0.w); ah0[3] += wv * bhi(u0.w);
      ac1[0] += wv * blo(u1.x); ac1[1] += wv * bhi(u1.x);
      ac1[2] += wv * blo(u1.y); ac1[3] += wv * bhi(u1.y);
      ah1[0] += wv * blo(u1.z); ah1[1] += wv * bhi(u1.z);
      ah1[2] += wv * blo(u1.w); ah1[3] += wv * bhi(u1.w);
    }
    float inv = 1.0f / (wsum + 1e-7f);
    float4 o0 = { ac0[0]*inv, ac0[1]*inv, ac0[2]*inv, ac0[3]*inv };
    float4 o1 = { ah0[0]*inv, ah0[1]*inv, ah0[2]*inv, ah0[3]*inv };
    float4 o2 = { ac1[0]*inv, ac1[1]*inv, ac1[2]*inv, ac1[3]*inv };
    float4 o3 = { ah1[0]*inv, ah1[1]*inv, ah1[2]*inv, ah1[3]*inv };
    ((float4*)c0L)[m * (SP / 4) + l] = o0;
    ((float4*)h0L)[m * (SP / 4) + l] = o1;
    ((float4*)c1L)[m * (SP / 4) + l] = o2;
    ((float4*)h1L)[m * (SP / 4) + l] = o3;
    if (l == 0) ipL[m] = wsum;
    if (!lstmLive) {  // batch death: persist exact f32 state for final_kernel
      ((float4*)Sc0g)[node * 32 + l] = o0;
      ((float4*)Sh0g)[node * 32 + l] = o1;
      ((float4*)Sc1g)[node * 32 + l] = o2;
      ((float4*)Sh1g)[node * 32 + l] = o3;
    }
  } else {
    // step 0: zero states, initial ip = [node==0]
    for (int i2 = tid; i2 < 16 * HH; i2 += 512) {
      int m = i2 >> 7, k = i2 & 127;
      c0L[m * SP + k] = 0.f; h0L[m * SP + k] = 0.f;
      c1L[m * SP + k] = 0.f; h1L[m * SP + k] = 0.f;
    }
    if (tid < 16) ipL[tid] = (((row0 + tid) & (NN - 1)) == 0) ? 1.0f : 0.0f;
  }
  if (!lstmLive) return;  // block-uniform

  const int exnode = exi[b];
  const int exm = exnode - (g16 * 16);
  __syncthreads();  // prologue state visible

  // pristine exit-row copy
  if (exm >= 0 && exm < 16 && tid < 128) {
    exitP[tid] = c0L[exm * SP + tid];
    exitP[128 + tid] = h0L[exm * SP + tid];
    exitP[256 + tid] = c1L[exm * SP + tid];
    exitP[384 + tid] = h1L[exm * SP + tid];
  }

  // c-state into registers; build bf16 h A-fragments into buffer 0
  float c0r[4], c1r[4], h0r[4], h1r[4];
#pragma unroll
  for (int r = 0; r < 4; ++r) {
    int m = qq * 4 + r;
    c0r[r] = c0L[m * SP + kcol];
    c1r[r] = c1L[m * SP + kcol];
    h0r[r] = h0L[m * SP + kcol];
    h1r[r] = h1L[m * SP + kcol];
    hA0[0][basePos + m * 8] = f2bu(h0r[r]);
    hA1[0][basePos + m * 8] = f2bu(h1r[r]);
  }
  __syncthreads();  // fragments ready

  int cur = 0;
  for (int t = 0; t < TT; ++t) {
    const int nxt = cur ^ 1;
    const s16x8* hA0c = (const s16x8*)hA0[cur];
    const s16x8* hA1c = (const s16x8*)hA1[cur];
    s16x8 a0[4], a1b[4];
#pragma unroll
    for (int kb = 0; kb < 4; ++kb) { a0[kb] = hA0c[kb * 64 + lane]; a1b[kb] = hA1c[kb * 64 + lane]; }
    f32x4 d0[4];
#pragma unroll
    for (int g = 0; g < 4; ++g) {
      int colz = (w + 8 * g) * 16 + n16;
#pragma unroll
      for (int r = 0; r < 4; ++r)
        d0[g][r] = tab[(size_t)toks[(qq * 4 + r) * 4 + t] * CC + colz];
    }

    // layer 0 MFMA: z = tab(+b0) + h0 @ Wh0
#pragma unroll
    for (int g = 0; g < 4; ++g)
#pragma unroll
      for (int kb = 0; kb < 4; ++kb)
        d0[g] = __builtin_amdgcn_mfma_f32_16x16x32_bf16(a0[kb], B0f[g][kb], d0[g], 0, 0, 0);

    // gates 0 in registers; new h0 frags -> OTHER buffer (no WAR hazard barrier)
#pragma unroll
    for (int r = 0; r < 4; ++r) {
      float cn = sigf(d0[1][r]) * c0r[r] + sigf(d0[0][r]) * tanhr(d0[2][r]);
      float hn = sigf(d0[3][r]) * tanhr(cn);
      c0r[r] = cn; h0r[r] = hn;
      hA0[nxt][basePos + (qq * 4 + r) * 8] = f2bu(hn);
    }
    __syncthreads();  // h0_new fragments visible

    // layer 1 MFMA: z = b1 + h0new @ Wi1 + h1old @ Wh1
    const s16x8* hA0n = (const s16x8*)hA0[nxt];
    s16x8 a1a[4];
#pragma unroll
    for (int kb = 0; kb < 4; ++kb) a1a[kb] = hA0n[kb * 64 + lane];
    f32x4 d1[4];
#pragma unroll
    for (int g = 0; g < 4; ++g) {
      int ci = w + 8 * g;
      s16x8 wi[4];
#pragma unroll
      for (int kb = 0; kb < 4; ++kb) wi[kb] = pWi1[(ci * 4 + kb) * 64 + lane];
      f32x4 d = { b1v[g], b1v[g], b1v[g], b1v[g] };
#pragma unroll
      for (int kb = 0; kb < 4; ++kb)
        d = __builtin_amdgcn_mfma_f32_16x16x32_bf16(a1a[kb], wi[kb], d, 0, 0, 0);
#pragma unroll
      for (int kb = 0; kb < 4; ++kb)
        d = __builtin_amdgcn_mfma_f32_16x16x32_bf16(a1b[kb], B1f[g][kb], d, 0, 0, 0);
      d1[g] = d;
    }

    // gates 1 in registers; new h1 frags -> OTHER buffer
#pragma unroll
    for (int r = 0; r < 4; ++r) {
      float cn = sigf(d1[1][r]) * c1r[r] + sigf(d1[0][r]) * tanhr(d1[2][r]);
      float hn = sigf(d1[3][r]) * tanhr(cn);
      c1r[r] = cn; h1r[r] = hn;
      hA1[nxt][basePos + (qq * 4 + r) * 8] = f2bu(hn);
    }
    __syncthreads();  // h1_new fragments visible for next token
    cur = nxt;
  }

  // epilogue: regs -> LDS
#pragma unroll
  for (int r = 0; r < 4; ++r) {
    int m = qq * 4 + r;
    c0L[m * SP + kcol] = c0r[r];
    h0L[m * SP + kcol] = h0r[r];
    c1L[m * SP + kcol] = c1r[r];
    h1L[m * SP + kcol] = h1r[r];
  }
  __syncthreads();

  // branch softmax (32 threads/row); exit row uses pristine copy
  {
    const int m = tid >> 5, sub = tid & 31;
    const int row = row0 + m;
    const bool isExit = (m == exm);
    float z0 = 0.f, z1 = 0.f;
#pragma unroll
    for (int u = 0; u < 16; ++u) {
      int k = u * 32 + sub;
      int seg = k >> 7, kk = k & 127;
      float fk;
      if (isExit) {
        fk = exitP[seg * 128 + kk];
      } else {
        fk = (seg == 0) ? c0L[m * SP + kk] : (seg == 1) ? h0L[m * SP + kk]
           : (seg == 2) ? c1L[m * SP + kk] : h1L[m * SP + kk];
      }
      z0 += fk * Wb[2 * k];
      z1 += fk * Wb[2 * k + 1];
    }
#pragma unroll
    for (int off = 16; off >= 1; off >>= 1) {
      z0 += __shfl_xor(z0, off);
      z1 += __shfl_xor(z1, off);
    }
    if (sub == 0) {
      z0 += bb[0]; z1 += bb[1];
      float mx = fmaxf(z0, z1);
      float e0 = __expf(z0 - mx), e1 = __expf(z1 - mx);
      float inv = 1.0f / (e0 + e1);
      float ipv = ipL[m];
      wtW[row] = e0 * inv * ipv;
      wfW[row] = e1 * inv * ipv;
    }
  }

  // writeout: pack to bf16, 2 x dwordx4 per lane; exit row from pristine copy
  {
    const int m = tid >> 5, l = tid & 31;
    const bool ex = (m == exm);
    const int grow = row0 + m;
    float f0[4], f1[4], f2[4], f3[4];
#pragma unroll
    for (int i = 0; i < 4; ++i) {
      int k = 4 * l + i;
      f0[i] = ex ? exitP[k] : c0L[m * SP + k];
      f1[i] = ex ? exitP[128 + k] : h0L[m * SP + k];
      f2[i] = ex ? exitP[256 + k] : c1L[m * SP + k];
      f3[i] = ex ? exitP[384 + k] : h1L[m * SP + k];
    }
    uint4 o0 = { packh(f0[0], f0[1]), packh(f0[2], f0[3]),
                 packh(f1[0], f1[1]), packh(f1[2], f1[3]) };
    uint4 o1 = { packh(f2[0], f2[1]), packh(f2[2], f2[3]),
                 packh(f3[0], f3[1]), packh(f3[2], f3[3]) };
    uint4* pw = (uint4*)(Pw + (size_t)grow * 256 + 8 * l);
    pw[0] = o0; pw[1] = o1;
  }
}

// logits: 64 blocks (16 batches x 4 col-tiles of 250), 256 threads, 1 output/thread
__global__ void final_kernel(const float* __restrict__ Sc0, const float* __restrict__ Sh0,
                             const float* __restrict__ Sc1, const float* __restrict__ Sh1,
                             const int* __restrict__ exi, const float* __restrict__ Wo,
                             const float* __restrict__ bo, float* __restrict__ out) {
  const int b = blockIdx.x >> 2;
  const int vt = blockIdx.x & 3;
  const int tid = threadIdx.x;  // 256
  __shared__ float f[512];
  int row = b * NN + exi[b];
  if (tid < 128) {
    size_t g = (size_t)row * HH + tid;
    f[tid] = Sc0[g];
    f[128 + tid] = Sh0[g];
    f[256 + tid] = Sc1[g];
    f[384 + tid] = Sh1[g];
  }
  __syncthreads();
  if (tid < 250) {
    int v = vt * 250 + tid;
    float acc = bo[v];
#pragma unroll 8
    for (int k = 0; k < 512; ++k) acc += f[k] * Wo[(size_t)k * OUTV + v];
    out[b * OUTV + v] = acc;
  }
}

// distinct failure signature if workspace too small: out := 0 -> err == ref absmax
__global__ void zero_out_kernel(float* __restrict__ out, int n) {
  int i = blockIdx.x * blockDim.x + threadIdx.x;
  if (i < n) out[i] = 0.0f;
}

// ---------------- host orchestration ----------------

extern "C" void kernel_launch(void* const* d_in, const int* in_sizes, int n_in,
                              void* d_out, int out_size, void* d_ws, size_t ws_size,
                              hipStream_t stream) {
  const int* data = (const int*)d_in[0];
  const int* tb   = (const int*)d_in[1];
  const int* fb   = (const int*)d_in[2];
  const int* exi  = (const int*)d_in[3];
  const int* steps = (const int*)d_in[4];
  const float* embed = (const float*)d_in[5];
  const float* Wi = (const float*)d_in[6];   // (L,H,4H)
  const float* Wh = (const float*)d_in[7];   // (L,H,4H)
  const float* bl = (const float*)d_in[8];   // (L,4H)
  const float* Wb = (const float*)d_in[9];   // (2LH,2)
  const float* bb = (const float*)d_in[10];  // (2,)
  const float* Wo = (const float*)d_in[11];  // (2LH,OUT)
  const float* bo = (const float*)d_in[12];  // (OUT,)
  float* out = (float*)d_out;

  const float* Wi0 = Wi;
  const float* Wi1 = Wi + HH * CC;
  const float* Wh0 = Wh;
  const float* Wh1 = Wh + HH * CC;
  const float* b0 = bl;
  const float* b1 = bl + CC;

  float* ws = (float*)d_ws;
  size_t off = 0;
  float* tab = ws + off;  off += (size_t)1024 * CC;        // 2 MB
  float* Sc0 = ws + off;  off += (size_t)MM * HH;          // death/final f32 bufs
  float* Sh0 = ws + off;  off += (size_t)MM * HH;
  float* Sc1 = ws + off;  off += (size_t)MM * HH;
  float* Sh1 = ws + off;  off += (size_t)MM * HH;
  unsigned int* PA = (unsigned int*)(ws + off); off += (size_t)MM * 256;  // packed state A
  unsigned int* PB = (unsigned int*)(ws + off); off += (size_t)MM * 256;  // packed state B
  unsigned short* swz = (unsigned short*)(ws + off); off += 3 * 32768;    // 3x65536 bf16
  float* wtA = ws + off;  off += MM;
  float* wfA = ws + off;  off += MM;
  float* wtB = ws + off;  off += MM;
  float* wfB = ws + off;  off += MM;
  int* offs  = (int*)(ws + off); off += MM + 16;
  int* edges = (int*)(ws + off); off += 2 * MM;
  (void)in_sizes; (void)n_in; (void)out_size;

  if (ws_size < off * sizeof(float)) {
    zero_out_kernel<<<(BB * OUTV + 255) / 256, 256, 0, stream>>>(out, BB * OUTV);
    return;
  }

  unsigned short* swzWh0 = swz;
  unsigned short* swzWi1 = swz + 65536;
  unsigned short* swzWh1 = swz + 2 * 65536;

  csr_kernel<<<BB, 512, 0, stream>>>(tb, fb, offs, edges);
  prep_kernel<<<893, 256, 0, stream>>>(Wh0, Wi1, Wh1, embed, Wi0, b0, swz, tab);

  // dispatch s: prologue aggregates step s-1 (reads other parity), LSTM writes parity s&1.
  for (int s = 0; s <= MAXS; ++s) {
    unsigned int* Pwp = (s & 1) ? PB : PA;
    const unsigned int* Prp = (s & 1) ? PA : PB;
    float* wtWp = (s & 1) ? wtB : wtA;
    float* wfWp = (s & 1) ? wfB : wfA;
    const float* wtRp = (s & 1) ? wtA : wtB;
    const float* wfRp = (s & 1) ? wfA : wfB;
    step_kernel<<<MM / 16, 512, 0, stream>>>(
        Sc0, Sh0, Sc1, Sh1, Prp, Pwp,
        wtRp, wfRp, wtWp, wfWp,
        offs, edges, tab, swzWh0, swzWi1, swzWh1, b1, Wb, bb,
        data, exi, steps, s);
  }
  final_kernel<<<BB * 4, 256, 0, stream>>>(Sc0, Sh0, Sc1, Sh1, exi, Wo, bo, out);
}